// Round 16
// baseline (289.380 us; speedup 1.0000x reference)
//
#include <hip/hip_runtime.h>
#include <math.h>

#define B_   2
#define S_   4096
#define HID_ 768
#define H_   12
#define D_   64
#define M_   64
#define CK_  33
#define BH_  (B_*H_)   // 24
#define KD_  768
#define NCH_ 32        // S-chunks (128 rows each)
#define SC_  128       // keys per chunk

typedef float  f32x4  __attribute__((ext_vector_type(4)));
typedef _Float16 f16x8 __attribute__((ext_vector_type(8)));
typedef unsigned short u16;

__device__ __forceinline__ u16 f2h_bits(float f) {
  union { _Float16 h; u16 u; } c; c.h = (_Float16)f; return c.u;
}
__device__ __forceinline__ float h2f(u16 b) {
  union { _Float16 h; u16 u; } c; c.u = b; return (float)c.h;
}
__device__ __forceinline__ void cvt8_hl(const float4 a, const float4 b,
                                        f16x8* hi, f16x8* lo) {
  const float v[8] = {a.x, a.y, a.z, a.w, b.x, b.y, b.z, b.w};
  f16x8 H, L;
#pragma unroll
  for (int e = 0; e < 8; ++e) {
    const _Float16 hh = (_Float16)v[e];
    H[e] = hh;
    L[e] = (_Float16)(v[e] - (float)hh);
  }
  *hi = H; *lo = L;
}
__device__ __forceinline__ void wsplit(u16* Hh, u16* Hl, int idx, float v) {
  const _Float16 hh = (_Float16)v;
  Hh[idx] = f2h_bits(v);
  Hl[idx] = f2h_bits(v - (float)hh);
}

// =============================================================
// Downcast: x -> Xh, qkv_w -> Wqh, out_w -> Woh (fp16 hi only)
// =============================================================
#define N8X  786432
#define N8WQ 221184
#define N8WO 73728
__global__ __launch_bounds__(256) void split3(
    const float* __restrict__ x, const float* __restrict__ qkv_w,
    const float* __restrict__ out_w,
    u16* __restrict__ Xh, u16* __restrict__ Wqh, u16* __restrict__ Woh)
{
  const int i = blockIdx.x * 256 + threadIdx.x;
  const float* src; u16* dst; int j;
  if (i < N8X)                 { src = x;     dst = Xh;  j = i; }
  else if (i < N8X + N8WQ)     { src = qkv_w; dst = Wqh; j = i - N8X; }
  else if (i < N8X + N8WQ + N8WO) { src = out_w; dst = Woh; j = i - N8X - N8WQ; }
  else return;
  const float4 a = ((const float4*)src)[2 * j], b = ((const float4*)src)[2 * j + 1];
  const float v[8] = {a.x, a.y, a.z, a.w, b.x, b.y, b.z, b.w};
  union { u16 u[8]; uint4 q; } hv;
#pragma unroll
  for (int e = 0; e < 8; ++e) hv.u[e] = f2h_bits(v[e]);
  ((uint4*)dst)[j] = hv.q;
}

// =============================================================
// REGISTER-DIRECT fp16 MFMA GEMM: C = A @ W^T (+bias). NO LDS.
// Block = 128x128 tile = 4 waves x 64x64. Fragments loaded straight
// from global into VGPRs (f16x8 per lane), 2-deep ping-pong pipeline.
// MODE 0: scatter Q/K/V fp16, fused landmarks. MODE 1: row-major f32.
// =============================================================
template<int MODE>
__global__ __launch_bounds__(256) void gemm_reg(
    const u16* __restrict__ Ahg, const u16* __restrict__ Bhg,
    const float* __restrict__ bias,
    float* __restrict__ oF, u16* __restrict__ oQ, u16* __restrict__ oK,
    u16* __restrict__ oV,
    float* __restrict__ Ql, float* __restrict__ Kl, u16* __restrict__ Klh)
{
  constexpr int NBX = (MODE == 0) ? 18 : 6;
  constexpr int NT  = KD_ / 32;             // 24
  constexpr int NWG = NBX * 64;
  constexpr int CPX = NWG / 8;

  const int tid = threadIdx.x;
  const int lin = blockIdx.y * NBX + blockIdx.x;
  const int swb = (lin & 7) * CPX + (lin >> 3);     // XCD-contiguous chunks
  const int m0 = (swb / NBX) * 128;
  const int n0 = (swb % NBX) * 128;

  const int wave = tid >> 6, lane = tid & 63;
  const int wm = wave >> 1, wn = wave & 1;
  const int lr = lane & 15, kg = lane >> 4;

  const u16* pA = Ahg + (size_t)(m0 + wm * 64 + lr) * KD_ + kg * 8;
  const u16* pB = Bhg + (size_t)(n0 + wn * 64 + lr) * KD_ + kg * 8;

  f32x4 acc[4][4];
#pragma unroll
  for (int i = 0; i < 4; ++i)
#pragma unroll
    for (int j = 0; j < 4; ++j) acc[i][j] = (f32x4){0.f, 0.f, 0.f, 0.f};

  f16x8 a0[4], b0[4], a1[4], b1[4];

#define LDFRAG(ad, bd, kt_) do {                                         \
    _Pragma("unroll")                                                    \
    for (int q_ = 0; q_ < 4; ++q_) {                                     \
      ad[q_] = *(const f16x8*)&pA[(size_t)(q_ * 16) * KD_ + (kt_) * 32]; \
      bd[q_] = *(const f16x8*)&pB[(size_t)(q_ * 16) * KD_ + (kt_) * 32]; \
    }                                                                    \
  } while (0)

#define DOMM(av, bv) do {                                                \
    _Pragma("unroll")                                                    \
    for (int i_ = 0; i_ < 4; ++i_)                                       \
      _Pragma("unroll")                                                  \
      for (int j_ = 0; j_ < 4; ++j_)                                     \
        acc[i_][j_] = __builtin_amdgcn_mfma_f32_16x16x32_f16(            \
            av[i_], bv[j_], acc[i_][j_], 0, 0, 0);                       \
  } while (0)

  LDFRAG(a0, b0, 0);
  LDFRAG(a1, b1, 1);
  for (int kt = 0; kt < NT - 2; kt += 2) {
    DOMM(a0, b0);
    LDFRAG(a0, b0, kt + 2);
    DOMM(a1, b1);
    LDFRAG(a1, b1, kt + 3);
  }
  DOMM(a0, b0);
  DOMM(a1, b1);
#undef LDFRAG
#undef DOMM

  if (MODE == 0) {
    const int part = n0 / 768;
    const int within0 = n0 + wn * 64 - part * 768;
    const int h0 = within0 >> 6;
    u16* base = (part == 0) ? oQ : ((part == 1) ? oK : oV);
#pragma unroll
    for (int i = 0; i < 4; ++i) {
      const int mbase = m0 + wm * 64 + i * 16 + kg * 4;
#pragma unroll
      for (int j = 0; j < 4; ++j) {
        const int d = j * 16 + lr;
        const float bv = bias[n0 + wn * 64 + d];
#pragma unroll
        for (int r = 0; r < 4; ++r) {
          const int row = mbase + r;
          const int b = row >> 12, s = row & (S_ - 1);
          base[(((size_t)(b * H_ + h0) * S_ + s) << 6) + d] = f2h_bits(acc[i][j][r] + bv);
        }
      }
    }
    // landmarks: wave's 64 rows = one full segment of one (b, h0)
    if (part < 2) {
      const int rowseg = m0 + wm * 64;
      const int b = rowseg >> 12;
      const int seg = (rowseg & (S_ - 1)) >> 6;
      const int bhh = b * H_ + h0;
      float* dst = (part == 0) ? Ql : Kl;
#pragma unroll
      for (int j = 0; j < 4; ++j) {
        float sj = 0.f;
#pragma unroll
        for (int i = 0; i < 4; ++i)
#pragma unroll
          for (int r = 0; r < 4; ++r) sj += acc[i][j][r];
        sj += __shfl_xor(sj, 16);
        sj += __shfl_xor(sj, 32);
        if (kg == 0) {
          const int d = j * 16 + lr;
          const float lm = sj * (1.f / 64.f) + bias[n0 + wn * 64 + d];
          dst[((size_t)bhh * M_ + seg) * 64 + d] = lm;
          if (part == 1) Klh[((size_t)bhh * M_ + seg) * 64 + d] = f2h_bits(lm);
        }
      }
    }
  } else {
#pragma unroll
    for (int i = 0; i < 4; ++i) {
      const int mbase = m0 + wm * 64 + i * 16 + kg * 4;
#pragma unroll
      for (int j = 0; j < 4; ++j) {
        const int ncol = n0 + wn * 64 + j * 16 + lr;
        const float bv = bias[ncol];
#pragma unroll
        for (int r = 0; r < 4; ++r) {
          const int row = mbase + r;
          oF[(size_t)row * HID_ + ncol] = acc[i][j][r] + bv;
        }
      }
    }
  }
}

// =============================================================
// kernel_2 softmax + per-(b,h) max col/row sums (unchanged)
// =============================================================
__global__ __launch_bounds__(256) void kernel2_softmax(
    const float* __restrict__ Ql, const float* __restrict__ Kl,
    float* __restrict__ K2, float* __restrict__ colmax, float* __restrict__ rowmax)
{
  __shared__ float Qs[64][68], Ks[64][68], S2[64][68];
  __shared__ float red1[64], red2[64];
  const int bh = blockIdx.x, tid = threadIdx.x;
  for (int idx = tid; idx < 4096; idx += 256) {
    const int r = idx >> 6, c = idx & 63;
    Qs[r][c] = Ql[(size_t)bh * 4096 + idx];
    Ks[r][c] = Kl[(size_t)bh * 4096 + idx];
  }
  __syncthreads();
  for (int idx = tid; idx < 4096; idx += 256) {
    const int r = idx >> 6, c = idx & 63;
    float dot = 0.f;
#pragma unroll
    for (int k = 0; k < 64; k += 4) {
      const float4 a = *(const float4*)&Qs[r][k];
      const float4 b = *(const float4*)&Ks[c][k];
      dot += a.x * b.x + a.y * b.y + a.z * b.z + a.w * b.w;
    }
    S2[r][c] = dot * 0.125f;
  }
  __syncthreads();
  if (tid < 64) {
    const int r = tid;
    float mx = -1e30f;
    for (int c = 0; c < 64; ++c) mx = fmaxf(mx, S2[r][c]);
    float sum = 0.f;
    for (int c = 0; c < 64; ++c) { const float e = expf(S2[r][c] - mx); S2[r][c] = e; sum += e; }
    const float inv = 1.f / sum;
    for (int c = 0; c < 64; ++c) S2[r][c] *= inv;
  }
  __syncthreads();
  for (int idx = tid; idx < 4096; idx += 256)
    K2[(size_t)bh * 4096 + idx] = S2[idx >> 6][idx & 63];
  if (tid < 64) {
    float cs = 0.f, rs = 0.f;
    for (int m = 0; m < 64; ++m) { cs += S2[m][tid]; rs += S2[tid][m]; }
    red1[tid] = cs; red2[tid] = rs;
  }
  __syncthreads();
  if (tid == 0) {
    float mc = 0.f, mr = 0.f;
    for (int i = 0; i < 64; ++i) { mc = fmaxf(mc, red1[i]); mr = fmaxf(mr, red2[i]); }
    colmax[bh] = mc; rowmax[bh] = mr;
  }
}

// =============================================================
// MFMA Newton-Schulz + combine + W2 (unchanged from round 13)
// =============================================================
#define NST 88
__device__ __forceinline__ void mfma64x64(
    const u16* Ah, const u16* Al, const u16* Bh, const u16* Bl,
    int wave, int lr, int kg, f32x4 C[4])
{
#pragma unroll
  for (int j = 0; j < 4; ++j) C[j] = (f32x4){0.f, 0.f, 0.f, 0.f};
#pragma unroll
  for (int kk = 0; kk < 2; ++kk) {
    const int ao = (wave * 16 + lr) * NST + kk * 32 + kg * 8;
    const f16x8 ah = *(const f16x8*)&Ah[ao];
    const f16x8 al = *(const f16x8*)&Al[ao];
#pragma unroll
    for (int j = 0; j < 4; ++j) {
      const int bo = (j * 16 + lr) * NST + kk * 32 + kg * 8;
      const f16x8 bh = *(const f16x8*)&Bh[bo];
      const f16x8 bl = *(const f16x8*)&Bl[bo];
      C[j] = __builtin_amdgcn_mfma_f32_16x16x32_f16(ah, bh, C[j], 0, 0, 0);
      C[j] = __builtin_amdgcn_mfma_f32_16x16x32_f16(ah, bl, C[j], 0, 0, 0);
      C[j] = __builtin_amdgcn_mfma_f32_16x16x32_f16(al, bh, C[j], 0, 0, 0);
    }
  }
}

__global__ __launch_bounds__(256) void newton_combine(
    const float* __restrict__ K2, const float* __restrict__ colmax,
    const float* __restrict__ rowmax,
    const float* __restrict__ Opart, const float* __restrict__ mpart,
    const float* __restrict__ lpart, float* __restrict__ W2)
{
  __shared__ __align__(16) u16 K2h[64*NST], K2l[64*NST];
  __shared__ __align__(16) u16 Vh_[64*NST], Vl_[64*NST];
  __shared__ __align__(16) u16 VTh[64*NST], VTl[64*NST];
  __shared__ __align__(16) u16 KVh[64*NST], KVl[64*NST];
  __shared__ __align__(16) u16 TTh[64*NST], TTl[64*NST];
  __shared__ float w_[64][33];
  __shared__ float scale_s;

  const int bh = blockIdx.x, tid = threadIdx.x;
  const int wave = tid >> 6, lane = tid & 63;
  const int lr = lane & 15, kg = lane >> 4;

  if (tid == 0) {
    float mc = 0.f, mr = 0.f;
    for (int i = 0; i < BH_; ++i) { mc = fmaxf(mc, colmax[i]); mr = fmaxf(mr, rowmax[i]); }
    scale_s = 1.f / (mc * mr);
  }
  __syncthreads();
  const float scale = scale_s;

  for (int idx = tid; idx < 4096; idx += 256) {
    const int r = idx >> 6, c = idx & 63;
    const float v = K2[(size_t)bh * 4096 + idx];
    wsplit(K2h, K2l, r * NST + c, v);
    const float sv = scale * v;
    wsplit(VTh, VTl, r * NST + c, sv);
    wsplit(Vh_, Vl_, c * NST + r, sv);
  }
  __syncthreads();

  f32x4 C[4];
  for (int it = 0; it < 6; ++it) {
    mfma64x64(K2h, K2l, VTh, VTl, wave, lr, kg, C);
#pragma unroll
    for (int j = 0; j < 4; ++j)
#pragma unroll
      for (int r = 0; r < 4; ++r) {
        const int row = wave * 16 + kg * 4 + r, col = j * 16 + lr;
        const float kv = C[j][r];
        wsplit(KVh, KVl, row * NST + col, kv);
        wsplit(TTh, TTl, col * NST + row, (row == col ? 7.f : 0.f) - kv);
      }
    __syncthreads();
    mfma64x64(KVh, KVl, TTh, TTl, wave, lr, kg, C);
    __syncthreads();
#pragma unroll
    for (int j = 0; j < 4; ++j)
#pragma unroll
      for (int r = 0; r < 4; ++r) {
        const int row = wave * 16 + kg * 4 + r, col = j * 16 + lr;
        wsplit(TTh, TTl, col * NST + row, (row == col ? 15.f : 0.f) - C[j][r]);
      }
    __syncthreads();
    mfma64x64(KVh, KVl, TTh, TTl, wave, lr, kg, C);
    __syncthreads();
#pragma unroll
    for (int j = 0; j < 4; ++j)
#pragma unroll
      for (int r = 0; r < 4; ++r) {
        const int row = wave * 16 + kg * 4 + r, col = j * 16 + lr;
        wsplit(TTh, TTl, col * NST + row, (row == col ? 13.f : 0.f) - C[j][r]);
      }
    __syncthreads();
    mfma64x64(Vh_, Vl_, TTh, TTl, wave, lr, kg, C);
#pragma unroll
    for (int j = 0; j < 4; ++j)
#pragma unroll
      for (int r = 0; r < 4; ++r) {
        const int row = wave * 16 + kg * 4 + r, col = j * 16 + lr;
        const float v = 0.25f * C[j][r];
        wsplit(Vh_, Vl_, row * NST + col, v);
        wsplit(VTh, VTl, col * NST + row, v);
      }
    __syncthreads();
  }

  if (tid < 64) {
    const int m = tid;
    float Mx = -1e30f;
    for (int j = 0; j < NCH_; ++j)
      Mx = fmaxf(Mx, mpart[((size_t)bh * NCH_ + j) * 64 + m]);
    float denom = 0.f;
    for (int j = 0; j < NCH_; ++j)
      denom += expf(mpart[((size_t)bh * NCH_ + j) * 64 + m] - Mx) *
               lpart[((size_t)bh * NCH_ + j) * 64 + m];
    const float inv = 1.f / denom;
    for (int j = 0; j < NCH_; ++j)
      w_[m][j] = expf(mpart[((size_t)bh * NCH_ + j) * 64 + m] - Mx) * inv;
  }
  __syncthreads();
  u16* W1Th = K2h;
  u16* W1Tl = K2l;
  {
    const int mg = tid >> 4, dq = (tid & 15) * 4;
#pragma unroll
    for (int i = 0; i < 4; ++i) {
      const int m = mg * 4 + i;
      float4 acc = make_float4(0.f, 0.f, 0.f, 0.f);
      for (int j = 0; j < NCH_; ++j) {
        const float ww = w_[m][j];
        const float4 o = *(const float4*)&Opart[(((size_t)bh * NCH_ + j) * 64 + m) * 64 + dq];
        acc.x += ww * o.x; acc.y += ww * o.y; acc.z += ww * o.z; acc.w += ww * o.w;
      }
      wsplit(W1Th, W1Tl, (dq + 0) * NST + m, acc.x);
      wsplit(W1Th, W1Tl, (dq + 1) * NST + m, acc.y);
      wsplit(W1Th, W1Tl, (dq + 2) * NST + m, acc.z);
      wsplit(W1Th, W1Tl, (dq + 3) * NST + m, acc.w);
    }
  }
  __syncthreads();
  mfma64x64(Vh_, Vl_, W1Th, W1Tl, wave, lr, kg, C);
#pragma unroll
  for (int j = 0; j < 4; ++j)
#pragma unroll
    for (int r = 0; r < 4; ++r) {
      const int row = wave * 16 + kg * 4 + r, col = j * 16 + lr;
      W2[(size_t)bh * 4096 + row * 64 + col] = C[j][r];
    }
}

// =============================================================
// k3v pass 1 (unchanged)
// =============================================================
__global__ __launch_bounds__(256) void k3v_pass1(
    const float* __restrict__ Ql, const u16* __restrict__ Kh,
    const u16* __restrict__ Vh, float* __restrict__ Opart,
    float* __restrict__ mpart, float* __restrict__ lpart)
{
  __shared__ float P[64][129];
  __shared__ float red1[64][4], red2[64][4];

  const int ch = blockIdx.x;
  const int bh = blockIdx.y;
  const int tid = threadIdx.x;
  const int wave = tid >> 6, lane = tid & 63;
  const int lr = lane & 15, kg = lane >> 4;

  const float* Qlb = Ql + (size_t)bh * 4096;
  const u16*   Kb  = Kh + (size_t)bh * S_ * 64;
  const u16*   Vb  = Vh + (size_t)bh * S_ * 64;

  f16x8 ah[4][2], al[4][2];
#pragma unroll
  for (int mt = 0; mt < 4; ++mt)
#pragma unroll
    for (int kk = 0; kk < 2; ++kk) {
      const float* qr = Qlb + (size_t)(mt * 16 + lr) * 64 + kk * 32 + kg * 8;
      cvt8_hl(*(const float4*)qr, *(const float4*)(qr + 4), &ah[mt][kk], &al[mt][kk]);
    }

#pragma unroll
  for (int t = 0; t < 2; ++t) {
    const int s0 = (wave * 2 + t) * 16;
    const int srow = ch * SC_ + s0 + lr;
    f32x4 acc[4];
#pragma unroll
    for (int mt = 0; mt < 4; ++mt) acc[mt] = (f32x4){0.f, 0.f, 0.f, 0.f};
#pragma unroll
    for (int kk = 0; kk < 2; ++kk) {
      const f16x8 bhf = *(const f16x8*)&Kb[(size_t)srow * 64 + kk * 32 + kg * 8];
#pragma unroll
      for (int mt = 0; mt < 4; ++mt) {
        acc[mt] = __builtin_amdgcn_mfma_f32_16x16x32_f16(ah[mt][kk], bhf, acc[mt], 0, 0, 0);
        acc[mt] = __builtin_amdgcn_mfma_f32_16x16x32_f16(al[mt][kk], bhf, acc[mt], 0, 0, 0);
      }
    }
#pragma unroll
    for (int mt = 0; mt < 4; ++mt)
#pragma unroll
      for (int r = 0; r < 4; ++r)
        P[mt * 16 + kg * 4 + r][s0 + lr] = acc[mt][r] * 0.125f;
  }
  __syncthreads();

  const int r = tid >> 2, q = tid & 3;
  {
    float mx = -1e30f;
#pragma unroll
    for (int s = 0; s < 32; ++s) mx = fmaxf(mx, P[r][q * 32 + s]);
    red1[r][q] = mx;
  }
  __syncthreads();
  const float rowmax = fmaxf(fmaxf(red1[r][0], red1[r][1]),
                             fmaxf(red1[r][2], red1[r][3]));
  {
    float sum = 0.f;
#pragma unroll
    for (int s = 0; s < 32; ++s) {
      const float e = expf(P[r][q * 32 + s] - rowmax);
      P[r][q * 32 + s] = e;
      sum += e;
    }
    red2[r][q] = sum;
  }
  __syncthreads();
  if (q == 0) {
    const float rowsum = red2[r][0] + red2[r][1] + red2[r][2] + red2[r][3];
    mpart[((size_t)bh * NCH_ + ch) * 64 + r] = rowmax;
    lpart[((size_t)bh * NCH_ + ch) * 64 + r] = rowsum;
  }

  const int mg = tid >> 4, dq = (tid & 15) * 4;
  float4 oacc[4];
#pragma unroll
  for (int i = 0; i < 4; ++i) oacc[i] = make_float4(0.f, 0.f, 0.f, 0.f);
  for (int s = 0; s < SC_; ++s) {
    const ushort4 vv = *(const ushort4*)&Vb[(size_t)(ch * SC_ + s) * 64 + dq];
    const float4 v = make_float4(h2f(vv.x), h2f(vv.y), h2f(vv.z), h2f(vv.w));
#pragma unroll
    for (int i = 0; i < 4; ++i) {
      const float p = P[mg * 4 + i][s];
      oacc[i].x += p * v.x; oacc[i].y += p * v.y;
      oacc[i].z += p * v.z; oacc[i].w += p * v.w;
    }
  }
#pragma unroll
  for (int i = 0; i < 4; ++i) {
    const size_t o = (((size_t)bh * NCH_ + ch) * 64 + mg * 4 + i) * 64 + dq;
    *(float4*)&Opart[o] = oacc[i];
  }
}

// =============================================================
// FUSED attention + conv v4 (unchanged)
// =============================================================
__global__ __launch_bounds__(256) void attn_conv_fused(
    const u16* __restrict__ Qh, const u16* __restrict__ Klh,
    const float* __restrict__ W2, const u16* __restrict__ Vh,
    const float* __restrict__ cw, u16* __restrict__ Xch)
{
  __shared__ __align__(16) u16 smem[19456];
  __shared__ float cws[33];

  const int ch = blockIdx.x;
  const int bh = blockIdx.y;
  const int tid = threadIdx.x;
  const int wave = tid >> 6, lane = tid & 63;
  const int lr = lane & 15, kg = lane >> 4;
  const int b = bh / H_, h = bh % H_;
  const int s0 = ch * 128;

  u16* Ph   = smem;
  u16* W2Th = smem + 9728;
  u16* W2Tl = smem + 14592;

  if (tid < 33) cws[tid] = cw[h * 33 + tid];
  for (int idx = tid; idx < 4096; idx += 256) {
    const int m = idx >> 6, d = idx & 63;
    const float w = W2[(size_t)bh * 4096 + idx];
    const _Float16 hh = (_Float16)w;
    W2Th[d * 76 + m] = f2h_bits(w);
    W2Tl[d * 76 + m] = f2h_bits(w - (float)hh);
  }

  const u16* Klb = Klh + (size_t)bh * 4096;
  const u16* Qb  = Qh + (size_t)bh * S_ * 64;
  f16x8 bf[4][2];
#pragma unroll
  for (int nt = 0; nt < 4; ++nt)
#pragma unroll
    for (int kk = 0; kk < 2; ++kk)
      bf[nt][kk] = *(const f16x8*)&Klb[(size_t)(nt * 16 + lr) * 64 + kk * 32 + kg * 8];

  f32x4 sacc[2][4];
#pragma unroll
  for (int t = 0; t < 2; ++t) {
#pragma unroll
    for (int nt = 0; nt < 4; ++nt) sacc[t][nt] = (f32x4){0.f, 0.f, 0.f, 0.f};
    const int rloc = wave * 32 + t * 16;
    f16x8 af[2];
#pragma unroll
    for (int kk = 0; kk < 2; ++kk)
      af[kk] = *(const f16x8*)&Qb[(size_t)(s0 + rloc + lr) * 64 + kk * 32 + kg * 8];
#pragma unroll
    for (int kk = 0; kk < 2; ++kk)
#pragma unroll
      for (int nt = 0; nt < 4; ++nt)
        sacc[t][nt] = __builtin_amdgcn_mfma_f32_16x16x32_f16(af[kk], bf[nt][kk], sacc[t][nt], 0, 0, 0);
  }

#pragma unroll
  for (int t = 0; t < 2; ++t)
#pragma unroll
    for (int nt = 0; nt < 4; ++nt)
      sacc[t][nt] *= 0.125f;

  float rinv[2][4];
#pragma unroll
  for (int t = 0; t < 2; ++t) {
#pragma unroll
    for (int r = 0; r < 4; ++r) {
      float mx = fmaxf(fmaxf(sacc[t][0][r], sacc[t][1][r]),
                       fmaxf(sacc[t][2][r], sacc[t][3][r]));
      mx = fmaxf(mx, __shfl_xor(mx, 1));
      mx = fmaxf(mx, __shfl_xor(mx, 2));
      mx = fmaxf(mx, __shfl_xor(mx, 4));
      mx = fmaxf(mx, __shfl_xor(mx, 8));
      float sum = 0.f;
#pragma unroll
      for (int nt = 0; nt < 4; ++nt) {
        const float e = expf(sacc[t][nt][r] - mx);
        sacc[t][nt][r] = e;
        sum += e;
      }
      sum += __shfl_xor(sum, 1);
      sum += __shfl_xor(sum, 2);
      sum += __shfl_xor(sum, 4);
      sum += __shfl_xor(sum, 8);
      rinv[t][r] = 1.f / sum;
    }
  }

#pragma unroll
  for (int t = 0; t < 2; ++t)
#pragma unroll
    for (int nt = 0; nt < 4; ++nt)
#pragma unroll
      for (int r = 0; r < 4; ++r) {
        const int row = wave * 32 + t * 16 + kg * 4 + r;
        Ph[row * 76 + nt * 16 + lr] = f2h_bits(sacc[t][nt][r] * rinv[t][r]);
      }
  __syncthreads();

  f32x4 oacc[2][4];
#pragma unroll
  for (int t = 0; t < 2; ++t)
#pragma unroll
    for (int dt = 0; dt < 4; ++dt) oacc[t][dt] = (f32x4){0.f, 0.f, 0.f, 0.f};
#pragma unroll
  for (int kk = 0; kk < 2; ++kk) {
    f16x8 pa[2];
#pragma unroll
    for (int t = 0; t < 2; ++t)
      pa[t] = *(const f16x8*)&Ph[(wave * 32 + t * 16 + lr) * 76 + kk * 32 + kg * 8];
#pragma unroll
    for (int dt = 0; dt < 4; ++dt) {
      const f16x8 wh = *(const f16x8*)&W2Th[(dt * 16 + lr) * 76 + kk * 32 + kg * 8];
      const f16x8 wl = *(const f16x8*)&W2Tl[(dt * 16 + lr) * 76 + kk * 32 + kg * 8];
#pragma unroll
      for (int t = 0; t < 2; ++t) {
        oacc[t][dt] = __builtin_amdgcn_mfma_f32_16x16x32_f16(pa[t], wh, oacc[t][dt], 0, 0, 0);
        oacc[t][dt] = __builtin_amdgcn_mfma_f32_16x16x32_f16(pa[t], wl, oacc[t][dt], 0, 0, 0);
      }
    }
  }
  __syncthreads();

  float* O = (float*)smem;
#pragma unroll
  for (int t = 0; t < 2; ++t)
#pragma unroll
    for (int dt = 0; dt < 4; ++dt)
#pragma unroll
      for (int r = 0; r < 4; ++r) {
        const int row = wave * 32 + t * 16 + kg * 4 + r;
        O[row * 68 + dt * 16 + lr] = oacc[t][dt][r];
      }
  __syncthreads();

  const int d = tid & 63, rg = tid >> 6;
  const int rbase = s0 + rg * 32;
  const u16* Vd = Vh + (size_t)bh * S_ * 64 + d;

  float v[40];
#pragma unroll
  for (int j = 0; j < 40; ++j) {
    const int sv = rbase - 16 + j;
    v[j] = (sv >= 0 && sv < S_) ? h2f(Vd[(size_t)sv * 64]) : 0.f;
  }

#pragma clang loop unroll(disable)
  for (int c = 0; c < 4; ++c) {
#pragma unroll
    for (int rr = 0; rr < 8; ++rr) {
      float acc = 0.f;
#pragma unroll
      for (int t = 0; t < 33; ++t) acc += v[rr + t] * cws[t];
      const int row = rg * 32 + c * 8 + rr;
      const float oo = O[row * 68 + d] + acc;
      const size_t idx = ((size_t)(b * S_ + s0 + row)) * HID_ + h * 64 + d;
      Xch[idx] = f2h_bits(oo);
    }
    if (c < 3) {
#pragma unroll
      for (int j = 0; j < 32; ++j) v[j] = v[j + 8];
#pragma unroll
      for (int j = 0; j < 8; ++j) {
        const int sv = rbase + 24 + c * 8 + j;
        v[32 + j] = (sv >= 0 && sv < S_) ? h2f(Vd[(size_t)sv * 64]) : 0.f;
      }
    }
  }
}

// =============================================================
extern "C" void kernel_launch(void* const* d_in, const int* in_sizes, int n_in,
                              void* d_out, int out_size, void* d_ws, size_t ws_size,
                              hipStream_t stream)
{
  (void)in_sizes; (void)n_in; (void)out_size; (void)ws_size;
  const float* x      = (const float*)d_in[0];
  const float* qkv_w  = (const float*)d_in[1];
  const float* qkv_b  = (const float*)d_in[2];
  const float* conv_w = (const float*)d_in[3];
  const float* out_w  = (const float*)d_in[4];
  const float* out_b  = (const float*)d_in[5];
  float* out = (float*)d_out;

  float* ws = (float*)d_ws;
  u16* Qh = (u16*)ws;
  u16* Kh = Qh + 6291456;
  u16* Vh = Kh + 6291456;
  float* Ql = ws + 9437184;
  float* Kl = Ql + 98304;
  float* K2 = Kl + 98304;
  float* W2 = K2 + 98304;
  float* colmax = W2 + 98304;
  float* rowmax = colmax + 32;
  u16* Klh = (u16*)(rowmax + 32);
  float* nxt = rowmax + 32 + 49152;
  u16* Xh  = (u16*)nxt;
  u16* Xl  = Xh + 6291456;
  u16* Wqh = Xl + 6291456;
  u16* Woh = Wqh + 1769472;
  u16* Xch = Xh;
  float* Opart = (float*)Xh;
  float* mpart = (float*)Xl;
  float* lpart = mpart + BH_ * NCH_ * 64;

  split3<<<(N8X + N8WQ + N8WO + 255) / 256, 256, 0, stream>>>(
      x, qkv_w, out_w, Xh, Wqh, Woh);

  gemm_reg<0><<<dim3(18, 64), 256, 0, stream>>>(
      Xh, Wqh, qkv_b, nullptr, Qh, Kh, Vh, Ql, Kl, Klh);

  kernel2_softmax<<<BH_, 256, 0, stream>>>(Ql, Kl, K2, colmax, rowmax);

  k3v_pass1<<<dim3(NCH_, BH_), 256, 0, stream>>>(Ql, Kh, Vh, Opart, mpart, lpart);

  newton_combine<<<BH_, 256, 0, stream>>>(K2, colmax, rowmax,
                                          Opart, mpart, lpart, W2);

  attn_conv_fused<<<dim3(NCH_, BH_), 256, 0, stream>>>(
      Qh, Klh, W2, Vh, conv_w, Xch);

  gemm_reg<1><<<dim3(6, 64), 256, 0, stream>>>(
      Xch, Woh, out_b, out, nullptr, nullptr, nullptr,
      nullptr, nullptr, nullptr);
}

// Round 17
// 278.904 us; speedup vs baseline: 1.0376x; 1.0376x over previous
//
#include <hip/hip_runtime.h>
#include <math.h>

#define B_   2
#define S_   4096
#define HID_ 768
#define H_   12
#define D_   64
#define M_   64
#define CK_  33
#define BH_  (B_*H_)   // 24
#define KD_  768
#define NCH_ 32        // S-chunks (128 rows each)
#define SC_  128       // keys per chunk

typedef float  f32x4  __attribute__((ext_vector_type(4)));
typedef _Float16 f16x8 __attribute__((ext_vector_type(8)));
typedef unsigned short u16;

__device__ __forceinline__ u16 f2h_bits(float f) {
  union { _Float16 h; u16 u; } c; c.h = (_Float16)f; return c.u;
}
__device__ __forceinline__ float h2f(u16 b) {
  union { _Float16 h; u16 u; } c; c.u = b; return (float)c.h;
}
__device__ __forceinline__ void cvt8_hl(const float4 a, const float4 b,
                                        f16x8* hi, f16x8* lo) {
  const float v[8] = {a.x, a.y, a.z, a.w, b.x, b.y, b.z, b.w};
  f16x8 H, L;
#pragma unroll
  for (int e = 0; e < 8; ++e) {
    const _Float16 hh = (_Float16)v[e];
    H[e] = hh;
    L[e] = (_Float16)(v[e] - (float)hh);
  }
  *hi = H; *lo = L;
}
__device__ __forceinline__ void wsplit(u16* Hh, u16* Hl, int idx, float v) {
  const _Float16 hh = (_Float16)v;
  Hh[idx] = f2h_bits(v);
  Hl[idx] = f2h_bits(v - (float)hh);
}

// =============================================================
// Downcast: x -> Xh, qkv_w -> Wqh, out_w -> Woh (fp16 hi only)
// =============================================================
#define N8X  786432
#define N8WQ 221184
#define N8WO 73728
__global__ __launch_bounds__(256) void split3(
    const float* __restrict__ x, const float* __restrict__ qkv_w,
    const float* __restrict__ out_w,
    u16* __restrict__ Xh, u16* __restrict__ Wqh, u16* __restrict__ Woh)
{
  const int i = blockIdx.x * 256 + threadIdx.x;
  const float* src; u16* dst; int j;
  if (i < N8X)                 { src = x;     dst = Xh;  j = i; }
  else if (i < N8X + N8WQ)     { src = qkv_w; dst = Wqh; j = i - N8X; }
  else if (i < N8X + N8WQ + N8WO) { src = out_w; dst = Woh; j = i - N8X - N8WQ; }
  else return;
  const float4 a = ((const float4*)src)[2 * j], b = ((const float4*)src)[2 * j + 1];
  const float v[8] = {a.x, a.y, a.z, a.w, b.x, b.y, b.z, b.w};
  union { u16 u[8]; uint4 q; } hv;
#pragma unroll
  for (int e = 0; e < 8; ++e) hv.u[e] = f2h_bits(v[e]);
  ((uint4*)dst)[j] = hv.q;
}

// =============================================================
// K-SPLIT fp16 MFMA GEMM: C = A @ W^T (+bias)
// Block = 64x64 tile, 4 waves EACH computing the full tile over a
// private K-slice of 192 (6 K-steps) -> short serial chain, huge grid.
// Register-direct loads (no staging LDS), 2-deep ping-pong.
// Reduction: waves 0/1 write f32 regions, waves 2/3 add, epilogue sums.
// MODE 0: scatter Q/K/V fp16 + fused landmarks (block = 1 seg x 1 head).
// MODE 1: row-major f32 out.
// =============================================================
template<int MODE>
__global__ __launch_bounds__(256) void gemm_ksplit(
    const u16* __restrict__ Ahg, const u16* __restrict__ Bhg,
    const float* __restrict__ bias,
    float* __restrict__ oF, u16* __restrict__ oQ, u16* __restrict__ oK,
    u16* __restrict__ oV,
    float* __restrict__ Ql, float* __restrict__ Kl, u16* __restrict__ Klh)
{
  constexpr int NBX = (MODE == 0) ? 36 : 12;   // N / 64
  constexpr int NWG = NBX * 128;               // x (M/64 = 128)
  constexpr int CPX = NWG / 8;

  __shared__ float Rr[2][64][68];              // ~34.8 KB

  const int tid = threadIdx.x;
  const int lin = blockIdx.y * NBX + blockIdx.x;
  const int swb = (lin & 7) * CPX + (lin >> 3);     // XCD-contiguous chunks
  const int m0 = (swb / NBX) * 64;
  const int n0 = (swb % NBX) * 64;

  const int wave = tid >> 6, lane = tid & 63;
  const int lr = lane & 15, kg = lane >> 4;

  // wave's K-slice: [wave*192, wave*192+192), 6 steps of 32
  const u16* pA = Ahg + (size_t)(m0 + lr) * KD_ + wave * 192 + kg * 8;
  const u16* pB = Bhg + (size_t)(n0 + lr) * KD_ + wave * 192 + kg * 8;

  f32x4 acc[4][4];
#pragma unroll
  for (int i = 0; i < 4; ++i)
#pragma unroll
    for (int j = 0; j < 4; ++j) acc[i][j] = (f32x4){0.f, 0.f, 0.f, 0.f};

  f16x8 a0[4], b0[4], a1[4], b1[4];

#define LDFRAG(ad, bd, kt_) do {                                         \
    _Pragma("unroll")                                                    \
    for (int q_ = 0; q_ < 4; ++q_) {                                     \
      ad[q_] = *(const f16x8*)&pA[(size_t)(q_ * 16) * KD_ + (kt_) * 32]; \
      bd[q_] = *(const f16x8*)&pB[(size_t)(q_ * 16) * KD_ + (kt_) * 32]; \
    }                                                                    \
  } while (0)

#define DOMM(av, bv) do {                                                \
    _Pragma("unroll")                                                    \
    for (int i_ = 0; i_ < 4; ++i_)                                       \
      _Pragma("unroll")                                                  \
      for (int j_ = 0; j_ < 4; ++j_)                                     \
        acc[i_][j_] = __builtin_amdgcn_mfma_f32_16x16x32_f16(            \
            av[i_], bv[j_], acc[i_][j_], 0, 0, 0);                       \
  } while (0)

  LDFRAG(a0, b0, 0);
  LDFRAG(a1, b1, 1);
#pragma unroll
  for (int kt = 0; kt < 4; kt += 2) {
    DOMM(a0, b0);
    LDFRAG(a0, b0, kt + 2);
    DOMM(a1, b1);
    LDFRAG(a1, b1, kt + 3);
  }
  DOMM(a0, b0);
  DOMM(a1, b1);
#undef LDFRAG
#undef DOMM

  // ---- cross-wave K reduction ----
  if (wave < 2) {
#pragma unroll
    for (int i = 0; i < 4; ++i)
#pragma unroll
      for (int j = 0; j < 4; ++j)
#pragma unroll
        for (int r = 0; r < 4; ++r)
          Rr[wave][i * 16 + kg * 4 + r][j * 16 + lr] = acc[i][j][r];
  }
  __syncthreads();
  if (wave >= 2) {
#pragma unroll
    for (int i = 0; i < 4; ++i)
#pragma unroll
      for (int j = 0; j < 4; ++j)
#pragma unroll
        for (int r = 0; r < 4; ++r)
          Rr[wave - 2][i * 16 + kg * 4 + r][j * 16 + lr] += acc[i][j][r];
  }
  __syncthreads();

  // ---- epilogue: thread t -> row t>>2, cols (t&3)*16 .. +15 ----
  const int row = tid >> 2;
  const int c0 = (tid & 3) * 16;
  const int grow = m0 + row;
  const int b = grow >> 12, s = grow & (S_ - 1);

  if (MODE == 0) {
    const int part = n0 / 768;
    const int h0 = (n0 - part * 768) >> 6;
    u16* base = (part == 0) ? oQ : ((part == 1) ? oK : oV);
    const size_t obase = (((size_t)(b * H_ + h0) * S_ + s) << 6);
#pragma unroll
    for (int e = 0; e < 16; ++e) {
      const float val = Rr[0][row][c0 + e] + Rr[1][row][c0 + e] + bias[n0 + c0 + e];
      base[obase + c0 + e] = f2h_bits(val);
    }
    // landmarks: block = 1 full segment x 1 head
    if (part < 2 && tid < 64) {
      const int d = tid;
      float cs = 0.f;
      for (int r = 0; r < 64; ++r) cs += Rr[0][r][d] + Rr[1][r][d];
      const int seg = (m0 & (S_ - 1)) >> 6;
      const int bhh = b * H_ + h0;
      const float lm = cs * (1.f / 64.f) + bias[n0 + d];
      float* dst = (part == 0) ? Ql : Kl;
      dst[((size_t)bhh * M_ + seg) * 64 + d] = lm;
      if (part == 1) Klh[((size_t)bhh * M_ + seg) * 64 + d] = f2h_bits(lm);
    }
  } else {
#pragma unroll
    for (int e = 0; e < 16; ++e) {
      const float val = Rr[0][row][c0 + e] + Rr[1][row][c0 + e] + bias[n0 + c0 + e];
      oF[(size_t)grow * HID_ + n0 + c0 + e] = val;
    }
  }
}

// =============================================================
// kernel_2 softmax + per-(b,h) max col/row sums (unchanged)
// =============================================================
__global__ __launch_bounds__(256) void kernel2_softmax(
    const float* __restrict__ Ql, const float* __restrict__ Kl,
    float* __restrict__ K2, float* __restrict__ colmax, float* __restrict__ rowmax)
{
  __shared__ float Qs[64][68], Ks[64][68], S2[64][68];
  __shared__ float red1[64], red2[64];
  const int bh = blockIdx.x, tid = threadIdx.x;
  for (int idx = tid; idx < 4096; idx += 256) {
    const int r = idx >> 6, c = idx & 63;
    Qs[r][c] = Ql[(size_t)bh * 4096 + idx];
    Ks[r][c] = Kl[(size_t)bh * 4096 + idx];
  }
  __syncthreads();
  for (int idx = tid; idx < 4096; idx += 256) {
    const int r = idx >> 6, c = idx & 63;
    float dot = 0.f;
#pragma unroll
    for (int k = 0; k < 64; k += 4) {
      const float4 a = *(const float4*)&Qs[r][k];
      const float4 b = *(const float4*)&Ks[c][k];
      dot += a.x * b.x + a.y * b.y + a.z * b.z + a.w * b.w;
    }
    S2[r][c] = dot * 0.125f;
  }
  __syncthreads();
  if (tid < 64) {
    const int r = tid;
    float mx = -1e30f;
    for (int c = 0; c < 64; ++c) mx = fmaxf(mx, S2[r][c]);
    float sum = 0.f;
    for (int c = 0; c < 64; ++c) { const float e = expf(S2[r][c] - mx); S2[r][c] = e; sum += e; }
    const float inv = 1.f / sum;
    for (int c = 0; c < 64; ++c) S2[r][c] *= inv;
  }
  __syncthreads();
  for (int idx = tid; idx < 4096; idx += 256)
    K2[(size_t)bh * 4096 + idx] = S2[idx >> 6][idx & 63];
  if (tid < 64) {
    float cs = 0.f, rs = 0.f;
    for (int m = 0; m < 64; ++m) { cs += S2[m][tid]; rs += S2[tid][m]; }
    red1[tid] = cs; red2[tid] = rs;
  }
  __syncthreads();
  if (tid == 0) {
    float mc = 0.f, mr = 0.f;
    for (int i = 0; i < 64; ++i) { mc = fmaxf(mc, red1[i]); mr = fmaxf(mr, red2[i]); }
    colmax[bh] = mc; rowmax[bh] = mr;
  }
}

// =============================================================
// MFMA Newton-Schulz + combine + W2 (unchanged from round 13)
// =============================================================
#define NST 88
__device__ __forceinline__ void mfma64x64(
    const u16* Ah, const u16* Al, const u16* Bh, const u16* Bl,
    int wave, int lr, int kg, f32x4 C[4])
{
#pragma unroll
  for (int j = 0; j < 4; ++j) C[j] = (f32x4){0.f, 0.f, 0.f, 0.f};
#pragma unroll
  for (int kk = 0; kk < 2; ++kk) {
    const int ao = (wave * 16 + lr) * NST + kk * 32 + kg * 8;
    const f16x8 ah = *(const f16x8*)&Ah[ao];
    const f16x8 al = *(const f16x8*)&Al[ao];
#pragma unroll
    for (int j = 0; j < 4; ++j) {
      const int bo = (j * 16 + lr) * NST + kk * 32 + kg * 8;
      const f16x8 bh = *(const f16x8*)&Bh[bo];
      const f16x8 bl = *(const f16x8*)&Bl[bo];
      C[j] = __builtin_amdgcn_mfma_f32_16x16x32_f16(ah, bh, C[j], 0, 0, 0);
      C[j] = __builtin_amdgcn_mfma_f32_16x16x32_f16(ah, bl, C[j], 0, 0, 0);
      C[j] = __builtin_amdgcn_mfma_f32_16x16x32_f16(al, bh, C[j], 0, 0, 0);
    }
  }
}

__global__ __launch_bounds__(256) void newton_combine(
    const float* __restrict__ K2, const float* __restrict__ colmax,
    const float* __restrict__ rowmax,
    const float* __restrict__ Opart, const float* __restrict__ mpart,
    const float* __restrict__ lpart, float* __restrict__ W2)
{
  __shared__ __align__(16) u16 K2h[64*NST], K2l[64*NST];
  __shared__ __align__(16) u16 Vh_[64*NST], Vl_[64*NST];
  __shared__ __align__(16) u16 VTh[64*NST], VTl[64*NST];
  __shared__ __align__(16) u16 KVh[64*NST], KVl[64*NST];
  __shared__ __align__(16) u16 TTh[64*NST], TTl[64*NST];
  __shared__ float w_[64][33];
  __shared__ float scale_s;

  const int bh = blockIdx.x, tid = threadIdx.x;
  const int wave = tid >> 6, lane = tid & 63;
  const int lr = lane & 15, kg = lane >> 4;

  if (tid == 0) {
    float mc = 0.f, mr = 0.f;
    for (int i = 0; i < BH_; ++i) { mc = fmaxf(mc, colmax[i]); mr = fmaxf(mr, rowmax[i]); }
    scale_s = 1.f / (mc * mr);
  }
  __syncthreads();
  const float scale = scale_s;

  for (int idx = tid; idx < 4096; idx += 256) {
    const int r = idx >> 6, c = idx & 63;
    const float v = K2[(size_t)bh * 4096 + idx];
    wsplit(K2h, K2l, r * NST + c, v);
    const float sv = scale * v;
    wsplit(VTh, VTl, r * NST + c, sv);
    wsplit(Vh_, Vl_, c * NST + r, sv);
  }
  __syncthreads();

  f32x4 C[4];
  for (int it = 0; it < 6; ++it) {
    mfma64x64(K2h, K2l, VTh, VTl, wave, lr, kg, C);
#pragma unroll
    for (int j = 0; j < 4; ++j)
#pragma unroll
      for (int r = 0; r < 4; ++r) {
        const int row = wave * 16 + kg * 4 + r, col = j * 16 + lr;
        const float kv = C[j][r];
        wsplit(KVh, KVl, row * NST + col, kv);
        wsplit(TTh, TTl, col * NST + row, (row == col ? 7.f : 0.f) - kv);
      }
    __syncthreads();
    mfma64x64(KVh, KVl, TTh, TTl, wave, lr, kg, C);
    __syncthreads();
#pragma unroll
    for (int j = 0; j < 4; ++j)
#pragma unroll
      for (int r = 0; r < 4; ++r) {
        const int row = wave * 16 + kg * 4 + r, col = j * 16 + lr;
        wsplit(TTh, TTl, col * NST + row, (row == col ? 15.f : 0.f) - C[j][r]);
      }
    __syncthreads();
    mfma64x64(KVh, KVl, TTh, TTl, wave, lr, kg, C);
    __syncthreads();
#pragma unroll
    for (int j = 0; j < 4; ++j)
#pragma unroll
      for (int r = 0; r < 4; ++r) {
        const int row = wave * 16 + kg * 4 + r, col = j * 16 + lr;
        wsplit(TTh, TTl, col * NST + row, (row == col ? 13.f : 0.f) - C[j][r]);
      }
    __syncthreads();
    mfma64x64(Vh_, Vl_, TTh, TTl, wave, lr, kg, C);
#pragma unroll
    for (int j = 0; j < 4; ++j)
#pragma unroll
      for (int r = 0; r < 4; ++r) {
        const int row = wave * 16 + kg * 4 + r, col = j * 16 + lr;
        const float v = 0.25f * C[j][r];
        wsplit(Vh_, Vl_, row * NST + col, v);
        wsplit(VTh, VTl, col * NST + row, v);
      }
    __syncthreads();
  }

  if (tid < 64) {
    const int m = tid;
    float Mx = -1e30f;
    for (int j = 0; j < NCH_; ++j)
      Mx = fmaxf(Mx, mpart[((size_t)bh * NCH_ + j) * 64 + m]);
    float denom = 0.f;
    for (int j = 0; j < NCH_; ++j)
      denom += expf(mpart[((size_t)bh * NCH_ + j) * 64 + m] - Mx) *
               lpart[((size_t)bh * NCH_ + j) * 64 + m];
    const float inv = 1.f / denom;
    for (int j = 0; j < NCH_; ++j)
      w_[m][j] = expf(mpart[((size_t)bh * NCH_ + j) * 64 + m] - Mx) * inv;
  }
  __syncthreads();
  u16* W1Th = K2h;
  u16* W1Tl = K2l;
  {
    const int mg = tid >> 4, dq = (tid & 15) * 4;
#pragma unroll
    for (int i = 0; i < 4; ++i) {
      const int m = mg * 4 + i;
      float4 acc = make_float4(0.f, 0.f, 0.f, 0.f);
      for (int j = 0; j < NCH_; ++j) {
        const float ww = w_[m][j];
        const float4 o = *(const float4*)&Opart[(((size_t)bh * NCH_ + j) * 64 + m) * 64 + dq];
        acc.x += ww * o.x; acc.y += ww * o.y; acc.z += ww * o.z; acc.w += ww * o.w;
      }
      wsplit(W1Th, W1Tl, (dq + 0) * NST + m, acc.x);
      wsplit(W1Th, W1Tl, (dq + 1) * NST + m, acc.y);
      wsplit(W1Th, W1Tl, (dq + 2) * NST + m, acc.z);
      wsplit(W1Th, W1Tl, (dq + 3) * NST + m, acc.w);
    }
  }
  __syncthreads();
  mfma64x64(Vh_, Vl_, W1Th, W1Tl, wave, lr, kg, C);
#pragma unroll
  for (int j = 0; j < 4; ++j)
#pragma unroll
    for (int r = 0; r < 4; ++r) {
      const int row = wave * 16 + kg * 4 + r, col = j * 16 + lr;
      W2[(size_t)bh * 4096 + row * 64 + col] = C[j][r];
    }
}

// =============================================================
// k3v pass 1 (unchanged)
// =============================================================
__global__ __launch_bounds__(256) void k3v_pass1(
    const float* __restrict__ Ql, const u16* __restrict__ Kh,
    const u16* __restrict__ Vh, float* __restrict__ Opart,
    float* __restrict__ mpart, float* __restrict__ lpart)
{
  __shared__ float P[64][129];
  __shared__ float red1[64][4], red2[64][4];

  const int ch = blockIdx.x;
  const int bh = blockIdx.y;
  const int tid = threadIdx.x;
  const int wave = tid >> 6, lane = tid & 63;
  const int lr = lane & 15, kg = lane >> 4;

  const float* Qlb = Ql + (size_t)bh * 4096;
  const u16*   Kb  = Kh + (size_t)bh * S_ * 64;
  const u16*   Vb  = Vh + (size_t)bh * S_ * 64;

  f16x8 ah[4][2], al[4][2];
#pragma unroll
  for (int mt = 0; mt < 4; ++mt)
#pragma unroll
    for (int kk = 0; kk < 2; ++kk) {
      const float* qr = Qlb + (size_t)(mt * 16 + lr) * 64 + kk * 32 + kg * 8;
      cvt8_hl(*(const float4*)qr, *(const float4*)(qr + 4), &ah[mt][kk], &al[mt][kk]);
    }

#pragma unroll
  for (int t = 0; t < 2; ++t) {
    const int s0 = (wave * 2 + t) * 16;
    const int srow = ch * SC_ + s0 + lr;
    f32x4 acc[4];
#pragma unroll
    for (int mt = 0; mt < 4; ++mt) acc[mt] = (f32x4){0.f, 0.f, 0.f, 0.f};
#pragma unroll
    for (int kk = 0; kk < 2; ++kk) {
      const f16x8 bhf = *(const f16x8*)&Kb[(size_t)srow * 64 + kk * 32 + kg * 8];
#pragma unroll
      for (int mt = 0; mt < 4; ++mt) {
        acc[mt] = __builtin_amdgcn_mfma_f32_16x16x32_f16(ah[mt][kk], bhf, acc[mt], 0, 0, 0);
        acc[mt] = __builtin_amdgcn_mfma_f32_16x16x32_f16(al[mt][kk], bhf, acc[mt], 0, 0, 0);
      }
    }
#pragma unroll
    for (int mt = 0; mt < 4; ++mt)
#pragma unroll
      for (int r = 0; r < 4; ++r)
        P[mt * 16 + kg * 4 + r][s0 + lr] = acc[mt][r] * 0.125f;
  }
  __syncthreads();

  const int r = tid >> 2, q = tid & 3;
  {
    float mx = -1e30f;
#pragma unroll
    for (int s = 0; s < 32; ++s) mx = fmaxf(mx, P[r][q * 32 + s]);
    red1[r][q] = mx;
  }
  __syncthreads();
  const float rowmax = fmaxf(fmaxf(red1[r][0], red1[r][1]),
                             fmaxf(red1[r][2], red1[r][3]));
  {
    float sum = 0.f;
#pragma unroll
    for (int s = 0; s < 32; ++s) {
      const float e = expf(P[r][q * 32 + s] - rowmax);
      P[r][q * 32 + s] = e;
      sum += e;
    }
    red2[r][q] = sum;
  }
  __syncthreads();
  if (q == 0) {
    const float rowsum = red2[r][0] + red2[r][1] + red2[r][2] + red2[r][3];
    mpart[((size_t)bh * NCH_ + ch) * 64 + r] = rowmax;
    lpart[((size_t)bh * NCH_ + ch) * 64 + r] = rowsum;
  }

  const int mg = tid >> 4, dq = (tid & 15) * 4;
  float4 oacc[4];
#pragma unroll
  for (int i = 0; i < 4; ++i) oacc[i] = make_float4(0.f, 0.f, 0.f, 0.f);
  for (int s = 0; s < SC_; ++s) {
    const ushort4 vv = *(const ushort4*)&Vb[(size_t)(ch * SC_ + s) * 64 + dq];
    const float4 v = make_float4(h2f(vv.x), h2f(vv.y), h2f(vv.z), h2f(vv.w));
#pragma unroll
    for (int i = 0; i < 4; ++i) {
      const float p = P[mg * 4 + i][s];
      oacc[i].x += p * v.x; oacc[i].y += p * v.y;
      oacc[i].z += p * v.z; oacc[i].w += p * v.w;
    }
  }
#pragma unroll
  for (int i = 0; i < 4; ++i) {
    const size_t o = (((size_t)bh * NCH_ + ch) * 64 + mg * 4 + i) * 64 + dq;
    *(float4*)&Opart[o] = oacc[i];
  }
}

// =============================================================
// FUSED attention + conv v4 (unchanged)
// =============================================================
__global__ __launch_bounds__(256) void attn_conv_fused(
    const u16* __restrict__ Qh, const u16* __restrict__ Klh,
    const float* __restrict__ W2, const u16* __restrict__ Vh,
    const float* __restrict__ cw, u16* __restrict__ Xch)
{
  __shared__ __align__(16) u16 smem[19456];
  __shared__ float cws[33];

  const int ch = blockIdx.x;
  const int bh = blockIdx.y;
  const int tid = threadIdx.x;
  const int wave = tid >> 6, lane = tid & 63;
  const int lr = lane & 15, kg = lane >> 4;
  const int b = bh / H_, h = bh % H_;
  const int s0 = ch * 128;

  u16* Ph   = smem;
  u16* W2Th = smem + 9728;
  u16* W2Tl = smem + 14592;

  if (tid < 33) cws[tid] = cw[h * 33 + tid];
  for (int idx = tid; idx < 4096; idx += 256) {
    const int m = idx >> 6, d = idx & 63;
    const float w = W2[(size_t)bh * 4096 + idx];
    const _Float16 hh = (_Float16)w;
    W2Th[d * 76 + m] = f2h_bits(w);
    W2Tl[d * 76 + m] = f2h_bits(w - (float)hh);
  }

  const u16* Klb = Klh + (size_t)bh * 4096;
  const u16* Qb  = Qh + (size_t)bh * S_ * 64;
  f16x8 bf[4][2];
#pragma unroll
  for (int nt = 0; nt < 4; ++nt)
#pragma unroll
    for (int kk = 0; kk < 2; ++kk)
      bf[nt][kk] = *(const f16x8*)&Klb[(size_t)(nt * 16 + lr) * 64 + kk * 32 + kg * 8];

  f32x4 sacc[2][4];
#pragma unroll
  for (int t = 0; t < 2; ++t) {
#pragma unroll
    for (int nt = 0; nt < 4; ++nt) sacc[t][nt] = (f32x4){0.f, 0.f, 0.f, 0.f};
    const int rloc = wave * 32 + t * 16;
    f16x8 af[2];
#pragma unroll
    for (int kk = 0; kk < 2; ++kk)
      af[kk] = *(const f16x8*)&Qb[(size_t)(s0 + rloc + lr) * 64 + kk * 32 + kg * 8];
#pragma unroll
    for (int kk = 0; kk < 2; ++kk)
#pragma unroll
      for (int nt = 0; nt < 4; ++nt)
        sacc[t][nt] = __builtin_amdgcn_mfma_f32_16x16x32_f16(af[kk], bf[nt][kk], sacc[t][nt], 0, 0, 0);
  }

#pragma unroll
  for (int t = 0; t < 2; ++t)
#pragma unroll
    for (int nt = 0; nt < 4; ++nt)
      sacc[t][nt] *= 0.125f;

  float rinv[2][4];
#pragma unroll
  for (int t = 0; t < 2; ++t) {
#pragma unroll
    for (int r = 0; r < 4; ++r) {
      float mx = fmaxf(fmaxf(sacc[t][0][r], sacc[t][1][r]),
                       fmaxf(sacc[t][2][r], sacc[t][3][r]));
      mx = fmaxf(mx, __shfl_xor(mx, 1));
      mx = fmaxf(mx, __shfl_xor(mx, 2));
      mx = fmaxf(mx, __shfl_xor(mx, 4));
      mx = fmaxf(mx, __shfl_xor(mx, 8));
      float sum = 0.f;
#pragma unroll
      for (int nt = 0; nt < 4; ++nt) {
        const float e = expf(sacc[t][nt][r] - mx);
        sacc[t][nt][r] = e;
        sum += e;
      }
      sum += __shfl_xor(sum, 1);
      sum += __shfl_xor(sum, 2);
      sum += __shfl_xor(sum, 4);
      sum += __shfl_xor(sum, 8);
      rinv[t][r] = 1.f / sum;
    }
  }

#pragma unroll
  for (int t = 0; t < 2; ++t)
#pragma unroll
    for (int nt = 0; nt < 4; ++nt)
#pragma unroll
      for (int r = 0; r < 4; ++r) {
        const int row = wave * 32 + t * 16 + kg * 4 + r;
        Ph[row * 76 + nt * 16 + lr] = f2h_bits(sacc[t][nt][r] * rinv[t][r]);
      }
  __syncthreads();

  f32x4 oacc[2][4];
#pragma unroll
  for (int t = 0; t < 2; ++t)
#pragma unroll
    for (int dt = 0; dt < 4; ++dt) oacc[t][dt] = (f32x4){0.f, 0.f, 0.f, 0.f};
#pragma unroll
  for (int kk = 0; kk < 2; ++kk) {
    f16x8 pa[2];
#pragma unroll
    for (int t = 0; t < 2; ++t)
      pa[t] = *(const f16x8*)&Ph[(wave * 32 + t * 16 + lr) * 76 + kk * 32 + kg * 8];
#pragma unroll
    for (int dt = 0; dt < 4; ++dt) {
      const f16x8 wh = *(const f16x8*)&W2Th[(dt * 16 + lr) * 76 + kk * 32 + kg * 8];
      const f16x8 wl = *(const f16x8*)&W2Tl[(dt * 16 + lr) * 76 + kk * 32 + kg * 8];
#pragma unroll
      for (int t = 0; t < 2; ++t) {
        oacc[t][dt] = __builtin_amdgcn_mfma_f32_16x16x32_f16(pa[t], wh, oacc[t][dt], 0, 0, 0);
        oacc[t][dt] = __builtin_amdgcn_mfma_f32_16x16x32_f16(pa[t], wl, oacc[t][dt], 0, 0, 0);
      }
    }
  }
  __syncthreads();

  float* O = (float*)smem;
#pragma unroll
  for (int t = 0; t < 2; ++t)
#pragma unroll
    for (int dt = 0; dt < 4; ++dt)
#pragma unroll
      for (int r = 0; r < 4; ++r) {
        const int row = wave * 32 + t * 16 + kg * 4 + r;
        O[row * 68 + dt * 16 + lr] = oacc[t][dt][r];
      }
  __syncthreads();

  const int d = tid & 63, rg = tid >> 6;
  const int rbase = s0 + rg * 32;
  const u16* Vd = Vh + (size_t)bh * S_ * 64 + d;

  float v[40];
#pragma unroll
  for (int j = 0; j < 40; ++j) {
    const int sv = rbase - 16 + j;
    v[j] = (sv >= 0 && sv < S_) ? h2f(Vd[(size_t)sv * 64]) : 0.f;
  }

#pragma clang loop unroll(disable)
  for (int c = 0; c < 4; ++c) {
#pragma unroll
    for (int rr = 0; rr < 8; ++rr) {
      float acc = 0.f;
#pragma unroll
      for (int t = 0; t < 33; ++t) acc += v[rr + t] * cws[t];
      const int row = rg * 32 + c * 8 + rr;
      const float oo = O[row * 68 + d] + acc;
      const size_t idx = ((size_t)(b * S_ + s0 + row)) * HID_ + h * 64 + d;
      Xch[idx] = f2h_bits(oo);
    }
    if (c < 3) {
#pragma unroll
      for (int j = 0; j < 32; ++j) v[j] = v[j + 8];
#pragma unroll
      for (int j = 0; j < 8; ++j) {
        const int sv = rbase + 24 + c * 8 + j;
        v[32 + j] = (sv >= 0 && sv < S_) ? h2f(Vd[(size_t)sv * 64]) : 0.f;
      }
    }
  }
}

// =============================================================
extern "C" void kernel_launch(void* const* d_in, const int* in_sizes, int n_in,
                              void* d_out, int out_size, void* d_ws, size_t ws_size,
                              hipStream_t stream)
{
  (void)in_sizes; (void)n_in; (void)out_size; (void)ws_size;
  const float* x      = (const float*)d_in[0];
  const float* qkv_w  = (const float*)d_in[1];
  const float* qkv_b  = (const float*)d_in[2];
  const float* conv_w = (const float*)d_in[3];
  const float* out_w  = (const float*)d_in[4];
  const float* out_b  = (const float*)d_in[5];
  float* out = (float*)d_out;

  float* ws = (float*)d_ws;
  u16* Qh = (u16*)ws;
  u16* Kh = Qh + 6291456;
  u16* Vh = Kh + 6291456;
  float* Ql = ws + 9437184;
  float* Kl = Ql + 98304;
  float* K2 = Kl + 98304;
  float* W2 = K2 + 98304;
  float* colmax = W2 + 98304;
  float* rowmax = colmax + 32;
  u16* Klh = (u16*)(rowmax + 32);
  float* nxt = rowmax + 32 + 49152;
  u16* Xh  = (u16*)nxt;
  u16* Xl  = Xh + 6291456;
  u16* Wqh = Xl + 6291456;
  u16* Woh = Wqh + 1769472;
  u16* Xch = Xh;
  float* Opart = (float*)Xh;
  float* mpart = (float*)Xl;
  float* lpart = mpart + BH_ * NCH_ * 64;

  split3<<<(N8X + N8WQ + N8WO + 255) / 256, 256, 0, stream>>>(
      x, qkv_w, out_w, Xh, Wqh, Woh);

  gemm_ksplit<0><<<dim3(36, 128), 256, 0, stream>>>(
      Xh, Wqh, qkv_b, nullptr, Qh, Kh, Vh, Ql, Kl, Klh);

  kernel2_softmax<<<BH_, 256, 0, stream>>>(Ql, Kl, K2, colmax, rowmax);

  k3v_pass1<<<dim3(NCH_, BH_), 256, 0, stream>>>(Ql, Kh, Vh, Opart, mpart, lpart);

  newton_combine<<<BH_, 256, 0, stream>>>(K2, colmax, rowmax,
                                          Opart, mpart, lpart, W2);

  attn_conv_fused<<<dim3(NCH_, BH_), 256, 0, stream>>>(
      Qh, Klh, W2, Vh, conv_w, Xch);

  gemm_ksplit<1><<<dim3(12, 128), 256, 0, stream>>>(
      Xch, Woh, out_b, out, nullptr, nullptr, nullptr,
      nullptr, nullptr, nullptr);
}

// Round 18
// 202.168 us; speedup vs baseline: 1.4314x; 1.3796x over previous
//
#include <hip/hip_runtime.h>
#include <math.h>

#define B_   2
#define S_   4096
#define HID_ 768
#define H_   12
#define D_   64
#define M_   64
#define CK_  33
#define BH_  (B_*H_)   // 24
#define KD_  768
#define NCH_ 32        // S-chunks (128 rows each)
#define SC_  128       // keys per chunk

typedef float  f32x4  __attribute__((ext_vector_type(4)));
typedef _Float16 f16x8 __attribute__((ext_vector_type(8)));
typedef unsigned short u16;

__device__ __forceinline__ u16 f2h_bits(float f) {
  union { _Float16 h; u16 u; } c; c.h = (_Float16)f; return c.u;
}
__device__ __forceinline__ float h2f(u16 b) {
  union { _Float16 h; u16 u; } c; c.u = b; return (float)c.h;
}
__device__ __forceinline__ void cvt8_hl(const float4 a, const float4 b,
                                        f16x8* hi, f16x8* lo) {
  const float v[8] = {a.x, a.y, a.z, a.w, b.x, b.y, b.z, b.w};
  f16x8 H, L;
#pragma unroll
  for (int e = 0; e < 8; ++e) {
    const _Float16 hh = (_Float16)v[e];
    H[e] = hh;
    L[e] = (_Float16)(v[e] - (float)hh);
  }
  *hi = H; *lo = L;
}
__device__ __forceinline__ void wsplit(u16* Hh, u16* Hl, int idx, float v) {
  const _Float16 hh = (_Float16)v;
  Hh[idx] = f2h_bits(v);
  Hl[idx] = f2h_bits(v - (float)hh);
}

__device__ __forceinline__ void gld16(const void* g, void* l) {
  __builtin_amdgcn_global_load_lds(
      (const __attribute__((address_space(1))) void*)g,
      (__attribute__((address_space(3))) void*)l, 16, 0, 0);
}

// =============================================================
// Downcast: x -> Xh, qkv_w -> Wqh, out_w -> Woh (fp16 hi only)
// =============================================================
#define N8X  786432
#define N8WQ 221184
#define N8WO 73728
__global__ __launch_bounds__(256) void split3(
    const float* __restrict__ x, const float* __restrict__ qkv_w,
    const float* __restrict__ out_w,
    u16* __restrict__ Xh, u16* __restrict__ Wqh, u16* __restrict__ Woh)
{
  const int i = blockIdx.x * 256 + threadIdx.x;
  const float* src; u16* dst; int j;
  if (i < N8X)                 { src = x;     dst = Xh;  j = i; }
  else if (i < N8X + N8WQ)     { src = qkv_w; dst = Wqh; j = i - N8X; }
  else if (i < N8X + N8WQ + N8WO) { src = out_w; dst = Woh; j = i - N8X - N8WQ; }
  else return;
  const float4 a = ((const float4*)src)[2 * j], b = ((const float4*)src)[2 * j + 1];
  const float v[8] = {a.x, a.y, a.z, a.w, b.x, b.y, b.z, b.w};
  union { u16 u[8]; uint4 q; } hv;
#pragma unroll
  for (int e = 0; e < 8; ++e) hv.u[e] = f2h_bits(v[e]);
  ((uint4*)dst)[j] = hv.q;
}

// =============================================================
// fp16 MFMA GEMM (round-12 structure, single product): C = A @ W^T.
// 4 waves, global_load_lds dbuf staging, counted vmcnt + raw barriers.
// MODE 0: 128x64 tile, scatter Q/K/V fp16 + fused landmarks.
// MODE 1: 128x128 tile, row-major f32 out.
// =============================================================
template<int MODE>
__global__ __launch_bounds__(256) void gemm_bar(
    const u16* __restrict__ Ahg, const u16* __restrict__ Bhg,
    const float* __restrict__ bias,
    float* __restrict__ oF, u16* __restrict__ oQ, u16* __restrict__ oK,
    u16* __restrict__ oV,
    float* __restrict__ Ql, float* __restrict__ Kl, u16* __restrict__ Klh)
{
  constexpr int BM = 128;
  constexpr int BN = (MODE == 0) ? 64 : 128;
  constexpr int NBX = (MODE == 0) ? 36 : 6;
  constexpr int WN = BN / 2;
  constexpr int NF = WN / 16;
  constexpr int BINST = BN / 64;
  constexpr int ABUF = BM * 32;            // u16 per A buf
  constexpr int BUFSZ = ABUF + BN * 32;
  constexpr int NT = KD_ / 32;
  constexpr int NWG = NBX * 64;
  constexpr int CPX = NWG / 8;

  __shared__ __align__(16) u16 lds[2][BUFSZ];

  const int tid = threadIdx.x;
  const int lin = blockIdx.y * NBX + blockIdx.x;
  const int swb = (lin & 7) * CPX + (lin >> 3);   // XCD-contiguous chunks
  const int m0 = (swb / NBX) * BM;
  const int n0 = (swb % NBX) * BN;

  const int wave = tid >> 6, lane = tid & 63;
  const int wm = wave >> 1, wn = wave & 1;
  const int lr = lane & 15, kg = lane >> 4;

  const int srow = tid >> 2;
  const int swz_s = (tid >> 3) & 3;
  const int sk = ((tid & 3) ^ swz_s) * 8;

  const u16* pA = Ahg + (size_t)(m0 + srow) * KD_ + sk;
  const u16* pB = Bhg + (size_t)(n0 + srow) * KD_ + sk;

  f32x4 acc[4][NF];
#pragma unroll
  for (int i = 0; i < 4; ++i)
#pragma unroll
    for (int j = 0; j < NF; ++j) acc[i][j] = (f32x4){0.f, 0.f, 0.f, 0.f};

  const int rsw = (lr >> 1) & 3;
  const int kq = (kg ^ rsw) * 8;
  const int abase = (wm * 64 + lr) * 32 + kq;
  const int bbase = (wn * WN + lr) * 32 + kq;

#define STAGE_(buf, kt) do {                                              \
    const size_t go_ = (size_t)(kt) * 32;                                 \
    u16* L_ = &lds[buf][0];                                               \
    gld16(pA + go_,            L_ + tid * 8);                             \
    gld16(pA + go_ + 64 * KD_, L_ + 2048 + tid * 8);                      \
    gld16(pB + go_,            L_ + ABUF + tid * 8);                      \
    if (BINST == 2) gld16(pB + go_ + 64 * KD_, L_ + ABUF + 2048 + tid * 8); \
  } while (0)

  STAGE_(0, 0);

  int cur = 0;
  for (int kt = 0; kt < NT; ++kt) {
    if (kt + 1 < NT) {
      STAGE_(cur ^ 1, kt + 1);
      if constexpr (MODE == 0)
        asm volatile("s_waitcnt vmcnt(3)" ::: "memory");
      else
        asm volatile("s_waitcnt vmcnt(4)" ::: "memory");
    } else {
      asm volatile("s_waitcnt vmcnt(0)" ::: "memory");
    }
    __builtin_amdgcn_s_barrier();
    __builtin_amdgcn_sched_barrier(0);

    const u16* L_ = &lds[cur][0];
    f16x8 af[4], bf[NF];
#pragma unroll
    for (int i = 0; i < 4; ++i) af[i] = *(const f16x8*)&L_[abase + i * 512];
#pragma unroll
    for (int j = 0; j < NF; ++j) bf[j] = *(const f16x8*)&L_[ABUF + bbase + j * 512];
#pragma unroll
    for (int i = 0; i < 4; ++i)
#pragma unroll
      for (int j = 0; j < NF; ++j)
        acc[i][j] = __builtin_amdgcn_mfma_f32_16x16x32_f16(af[i], bf[j], acc[i][j], 0, 0, 0);

    __builtin_amdgcn_sched_barrier(0);
    __builtin_amdgcn_s_barrier();
    cur ^= 1;
  }
#undef STAGE_

  if (MODE == 0) {
    const int part = n0 / 768;
    const int h0 = (n0 - part * 768) >> 6;
    u16* base = (part == 0) ? oQ : ((part == 1) ? oK : oV);
#pragma unroll
    for (int i = 0; i < 4; ++i) {
      const int mbase = m0 + wm * 64 + i * 16 + kg * 4;
#pragma unroll
      for (int j = 0; j < NF; ++j) {
        const int d = wn * WN + j * 16 + lr;
        const float bv = bias[n0 + d];
#pragma unroll
        for (int r = 0; r < 4; ++r) {
          const int row = mbase + r;
          const int b = row >> 12, s = row & (S_ - 1);
          base[(((size_t)(b * H_ + h0) * S_ + s) << 6) + d] = f2h_bits(acc[i][j][r] + bv);
        }
      }
    }
    // landmarks: wave's 64 rows = one full segment of one (b, h0)
    if (part < 2) {
      const int rowseg = m0 + wm * 64;
      const int b = rowseg >> 12;
      const int seg = (rowseg & (S_ - 1)) >> 6;
      const int bhh = b * H_ + h0;
      float* dst = (part == 0) ? Ql : Kl;
#pragma unroll
      for (int j = 0; j < NF; ++j) {
        float sj = 0.f;
#pragma unroll
        for (int i = 0; i < 4; ++i)
#pragma unroll
          for (int r = 0; r < 4; ++r) sj += acc[i][j][r];
        sj += __shfl_xor(sj, 16);
        sj += __shfl_xor(sj, 32);
        if (kg == 0) {
          const int d = wn * WN + j * 16 + lr;
          const float lm = sj * (1.f / 64.f) + bias[n0 + d];
          dst[((size_t)bhh * M_ + seg) * 64 + d] = lm;
          if (part == 1) Klh[((size_t)bhh * M_ + seg) * 64 + d] = f2h_bits(lm);
        }
      }
    }
  } else {
#pragma unroll
    for (int i = 0; i < 4; ++i) {
      const int mbase = m0 + wm * 64 + i * 16 + kg * 4;
#pragma unroll
      for (int j = 0; j < NF; ++j) {
        const int ncol = n0 + wn * WN + j * 16 + lr;
        const float bv = bias[ncol];
#pragma unroll
        for (int r = 0; r < 4; ++r) {
          const int row = mbase + r;
          oF[(size_t)row * HID_ + ncol] = acc[i][j][r] + bv;
        }
      }
    }
  }
}

// =============================================================
// kernel_2 softmax + per-(b,h) max col/row sums (unchanged)
// =============================================================
__global__ __launch_bounds__(256) void kernel2_softmax(
    const float* __restrict__ Ql, const float* __restrict__ Kl,
    float* __restrict__ K2, float* __restrict__ colmax, float* __restrict__ rowmax)
{
  __shared__ float Qs[64][68], Ks[64][68], S2[64][68];
  __shared__ float red1[64], red2[64];
  const int bh = blockIdx.x, tid = threadIdx.x;
  for (int idx = tid; idx < 4096; idx += 256) {
    const int r = idx >> 6, c = idx & 63;
    Qs[r][c] = Ql[(size_t)bh * 4096 + idx];
    Ks[r][c] = Kl[(size_t)bh * 4096 + idx];
  }
  __syncthreads();
  for (int idx = tid; idx < 4096; idx += 256) {
    const int r = idx >> 6, c = idx & 63;
    float dot = 0.f;
#pragma unroll
    for (int k = 0; k < 64; k += 4) {
      const float4 a = *(const float4*)&Qs[r][k];
      const float4 b = *(const float4*)&Ks[c][k];
      dot += a.x * b.x + a.y * b.y + a.z * b.z + a.w * b.w;
    }
    S2[r][c] = dot * 0.125f;
  }
  __syncthreads();
  if (tid < 64) {
    const int r = tid;
    float mx = -1e30f;
    for (int c = 0; c < 64; ++c) mx = fmaxf(mx, S2[r][c]);
    float sum = 0.f;
    for (int c = 0; c < 64; ++c) { const float e = expf(S2[r][c] - mx); S2[r][c] = e; sum += e; }
    const float inv = 1.f / sum;
    for (int c = 0; c < 64; ++c) S2[r][c] *= inv;
  }
  __syncthreads();
  for (int idx = tid; idx < 4096; idx += 256)
    K2[(size_t)bh * 4096 + idx] = S2[idx >> 6][idx & 63];
  if (tid < 64) {
    float cs = 0.f, rs = 0.f;
    for (int m = 0; m < 64; ++m) { cs += S2[m][tid]; rs += S2[tid][m]; }
    red1[tid] = cs; red2[tid] = rs;
  }
  __syncthreads();
  if (tid == 0) {
    float mc = 0.f, mr = 0.f;
    for (int i = 0; i < 64; ++i) { mc = fmaxf(mc, red1[i]); mr = fmaxf(mr, red2[i]); }
    colmax[bh] = mc; rowmax[bh] = mr;
  }
}

// =============================================================
// MFMA Newton-Schulz + combine + W2 (unchanged from round 13)
// =============================================================
#define NST 88
__device__ __forceinline__ void mfma64x64(
    const u16* Ah, const u16* Al, const u16* Bh, const u16* Bl,
    int wave, int lr, int kg, f32x4 C[4])
{
#pragma unroll
  for (int j = 0; j < 4; ++j) C[j] = (f32x4){0.f, 0.f, 0.f, 0.f};
#pragma unroll
  for (int kk = 0; kk < 2; ++kk) {
    const int ao = (wave * 16 + lr) * NST + kk * 32 + kg * 8;
    const f16x8 ah = *(const f16x8*)&Ah[ao];
    const f16x8 al = *(const f16x8*)&Al[ao];
#pragma unroll
    for (int j = 0; j < 4; ++j) {
      const int bo = (j * 16 + lr) * NST + kk * 32 + kg * 8;
      const f16x8 bh = *(const f16x8*)&Bh[bo];
      const f16x8 bl = *(const f16x8*)&Bl[bo];
      C[j] = __builtin_amdgcn_mfma_f32_16x16x32_f16(ah, bh, C[j], 0, 0, 0);
      C[j] = __builtin_amdgcn_mfma_f32_16x16x32_f16(ah, bl, C[j], 0, 0, 0);
      C[j] = __builtin_amdgcn_mfma_f32_16x16x32_f16(al, bh, C[j], 0, 0, 0);
    }
  }
}

__global__ __launch_bounds__(256) void newton_combine(
    const float* __restrict__ K2, const float* __restrict__ colmax,
    const float* __restrict__ rowmax,
    const float* __restrict__ Opart, const float* __restrict__ mpart,
    const float* __restrict__ lpart, float* __restrict__ W2)
{
  __shared__ __align__(16) u16 K2h[64*NST], K2l[64*NST];
  __shared__ __align__(16) u16 Vh_[64*NST], Vl_[64*NST];
  __shared__ __align__(16) u16 VTh[64*NST], VTl[64*NST];
  __shared__ __align__(16) u16 KVh[64*NST], KVl[64*NST];
  __shared__ __align__(16) u16 TTh[64*NST], TTl[64*NST];
  __shared__ float w_[64][33];
  __shared__ float scale_s;

  const int bh = blockIdx.x, tid = threadIdx.x;
  const int wave = tid >> 6, lane = tid & 63;
  const int lr = lane & 15, kg = lane >> 4;

  if (tid == 0) {
    float mc = 0.f, mr = 0.f;
    for (int i = 0; i < BH_; ++i) { mc = fmaxf(mc, colmax[i]); mr = fmaxf(mr, rowmax[i]); }
    scale_s = 1.f / (mc * mr);
  }
  __syncthreads();
  const float scale = scale_s;

  for (int idx = tid; idx < 4096; idx += 256) {
    const int r = idx >> 6, c = idx & 63;
    const float v = K2[(size_t)bh * 4096 + idx];
    wsplit(K2h, K2l, r * NST + c, v);
    const float sv = scale * v;
    wsplit(VTh, VTl, r * NST + c, sv);
    wsplit(Vh_, Vl_, c * NST + r, sv);
  }
  __syncthreads();

  f32x4 C[4];
  for (int it = 0; it < 6; ++it) {
    mfma64x64(K2h, K2l, VTh, VTl, wave, lr, kg, C);
#pragma unroll
    for (int j = 0; j < 4; ++j)
#pragma unroll
      for (int r = 0; r < 4; ++r) {
        const int row = wave * 16 + kg * 4 + r, col = j * 16 + lr;
        const float kv = C[j][r];
        wsplit(KVh, KVl, row * NST + col, kv);
        wsplit(TTh, TTl, col * NST + row, (row == col ? 7.f : 0.f) - kv);
      }
    __syncthreads();
    mfma64x64(KVh, KVl, TTh, TTl, wave, lr, kg, C);
    __syncthreads();
#pragma unroll
    for (int j = 0; j < 4; ++j)
#pragma unroll
      for (int r = 0; r < 4; ++r) {
        const int row = wave * 16 + kg * 4 + r, col = j * 16 + lr;
        wsplit(TTh, TTl, col * NST + row, (row == col ? 15.f : 0.f) - C[j][r]);
      }
    __syncthreads();
    mfma64x64(KVh, KVl, TTh, TTl, wave, lr, kg, C);
    __syncthreads();
#pragma unroll
    for (int j = 0; j < 4; ++j)
#pragma unroll
      for (int r = 0; r < 4; ++r) {
        const int row = wave * 16 + kg * 4 + r, col = j * 16 + lr;
        wsplit(TTh, TTl, col * NST + row, (row == col ? 13.f : 0.f) - C[j][r]);
      }
    __syncthreads();
    mfma64x64(Vh_, Vl_, TTh, TTl, wave, lr, kg, C);
#pragma unroll
    for (int j = 0; j < 4; ++j)
#pragma unroll
      for (int r = 0; r < 4; ++r) {
        const int row = wave * 16 + kg * 4 + r, col = j * 16 + lr;
        const float v = 0.25f * C[j][r];
        wsplit(Vh_, Vl_, row * NST + col, v);
        wsplit(VTh, VTl, col * NST + row, v);
      }
    __syncthreads();
  }

  if (tid < 64) {
    const int m = tid;
    float Mx = -1e30f;
    for (int j = 0; j < NCH_; ++j)
      Mx = fmaxf(Mx, mpart[((size_t)bh * NCH_ + j) * 64 + m]);
    float denom = 0.f;
    for (int j = 0; j < NCH_; ++j)
      denom += expf(mpart[((size_t)bh * NCH_ + j) * 64 + m] - Mx) *
               lpart[((size_t)bh * NCH_ + j) * 64 + m];
    const float inv = 1.f / denom;
    for (int j = 0; j < NCH_; ++j)
      w_[m][j] = expf(mpart[((size_t)bh * NCH_ + j) * 64 + m] - Mx) * inv;
  }
  __syncthreads();
  u16* W1Th = K2h;
  u16* W1Tl = K2l;
  {
    const int mg = tid >> 4, dq = (tid & 15) * 4;
#pragma unroll
    for (int i = 0; i < 4; ++i) {
      const int m = mg * 4 + i;
      float4 acc = make_float4(0.f, 0.f, 0.f, 0.f);
      for (int j = 0; j < NCH_; ++j) {
        const float ww = w_[m][j];
        const float4 o = *(const float4*)&Opart[(((size_t)bh * NCH_ + j) * 64 + m) * 64 + dq];
        acc.x += ww * o.x; acc.y += ww * o.y; acc.z += ww * o.z; acc.w += ww * o.w;
      }
      wsplit(W1Th, W1Tl, (dq + 0) * NST + m, acc.x);
      wsplit(W1Th, W1Tl, (dq + 1) * NST + m, acc.y);
      wsplit(W1Th, W1Tl, (dq + 2) * NST + m, acc.z);
      wsplit(W1Th, W1Tl, (dq + 3) * NST + m, acc.w);
    }
  }
  __syncthreads();
  mfma64x64(Vh_, Vl_, W1Th, W1Tl, wave, lr, kg, C);
#pragma unroll
  for (int j = 0; j < 4; ++j)
#pragma unroll
    for (int r = 0; r < 4; ++r) {
      const int row = wave * 16 + kg * 4 + r, col = j * 16 + lr;
      W2[(size_t)bh * 4096 + row * 64 + col] = C[j][r];
    }
}

// =============================================================
// k3v pass 1 (unchanged)
// =============================================================
__global__ __launch_bounds__(256) void k3v_pass1(
    const float* __restrict__ Ql, const u16* __restrict__ Kh,
    const u16* __restrict__ Vh, float* __restrict__ Opart,
    float* __restrict__ mpart, float* __restrict__ lpart)
{
  __shared__ float P[64][129];
  __shared__ float red1[64][4], red2[64][4];

  const int ch = blockIdx.x;
  const int bh = blockIdx.y;
  const int tid = threadIdx.x;
  const int wave = tid >> 6, lane = tid & 63;
  const int lr = lane & 15, kg = lane >> 4;

  const float* Qlb = Ql + (size_t)bh * 4096;
  const u16*   Kb  = Kh + (size_t)bh * S_ * 64;
  const u16*   Vb  = Vh + (size_t)bh * S_ * 64;

  f16x8 ah[4][2], al[4][2];
#pragma unroll
  for (int mt = 0; mt < 4; ++mt)
#pragma unroll
    for (int kk = 0; kk < 2; ++kk) {
      const float* qr = Qlb + (size_t)(mt * 16 + lr) * 64 + kk * 32 + kg * 8;
      cvt8_hl(*(const float4*)qr, *(const float4*)(qr + 4), &ah[mt][kk], &al[mt][kk]);
    }

#pragma unroll
  for (int t = 0; t < 2; ++t) {
    const int s0 = (wave * 2 + t) * 16;
    const int srow = ch * SC_ + s0 + lr;
    f32x4 acc[4];
#pragma unroll
    for (int mt = 0; mt < 4; ++mt) acc[mt] = (f32x4){0.f, 0.f, 0.f, 0.f};
#pragma unroll
    for (int kk = 0; kk < 2; ++kk) {
      const f16x8 bhf = *(const f16x8*)&Kb[(size_t)srow * 64 + kk * 32 + kg * 8];
#pragma unroll
      for (int mt = 0; mt < 4; ++mt) {
        acc[mt] = __builtin_amdgcn_mfma_f32_16x16x32_f16(ah[mt][kk], bhf, acc[mt], 0, 0, 0);
        acc[mt] = __builtin_amdgcn_mfma_f32_16x16x32_f16(al[mt][kk], bhf, acc[mt], 0, 0, 0);
      }
    }
#pragma unroll
    for (int mt = 0; mt < 4; ++mt)
#pragma unroll
      for (int r = 0; r < 4; ++r)
        P[mt * 16 + kg * 4 + r][s0 + lr] = acc[mt][r] * 0.125f;
  }
  __syncthreads();

  const int r = tid >> 2, q = tid & 3;
  {
    float mx = -1e30f;
#pragma unroll
    for (int s = 0; s < 32; ++s) mx = fmaxf(mx, P[r][q * 32 + s]);
    red1[r][q] = mx;
  }
  __syncthreads();
  const float rowmax = fmaxf(fmaxf(red1[r][0], red1[r][1]),
                             fmaxf(red1[r][2], red1[r][3]));
  {
    float sum = 0.f;
#pragma unroll
    for (int s = 0; s < 32; ++s) {
      const float e = expf(P[r][q * 32 + s] - rowmax);
      P[r][q * 32 + s] = e;
      sum += e;
    }
    red2[r][q] = sum;
  }
  __syncthreads();
  if (q == 0) {
    const float rowsum = red2[r][0] + red2[r][1] + red2[r][2] + red2[r][3];
    mpart[((size_t)bh * NCH_ + ch) * 64 + r] = rowmax;
    lpart[((size_t)bh * NCH_ + ch) * 64 + r] = rowsum;
  }

  const int mg = tid >> 4, dq = (tid & 15) * 4;
  float4 oacc[4];
#pragma unroll
  for (int i = 0; i < 4; ++i) oacc[i] = make_float4(0.f, 0.f, 0.f, 0.f);
  for (int s = 0; s < SC_; ++s) {
    const ushort4 vv = *(const ushort4*)&Vb[(size_t)(ch * SC_ + s) * 64 + dq];
    const float4 v = make_float4(h2f(vv.x), h2f(vv.y), h2f(vv.z), h2f(vv.w));
#pragma unroll
    for (int i = 0; i < 4; ++i) {
      const float p = P[mg * 4 + i][s];
      oacc[i].x += p * v.x; oacc[i].y += p * v.y;
      oacc[i].z += p * v.z; oacc[i].w += p * v.w;
    }
  }
#pragma unroll
  for (int i = 0; i < 4; ++i) {
    const size_t o = (((size_t)bh * NCH_ + ch) * 64 + mg * 4 + i) * 64 + dq;
    *(float4*)&Opart[o] = oacc[i];
  }
}

// =============================================================
// FUSED attention + conv v4 (Xch hi-only out)
// =============================================================
__global__ __launch_bounds__(256) void attn_conv_fused(
    const u16* __restrict__ Qh, const u16* __restrict__ Klh,
    const float* __restrict__ W2, const u16* __restrict__ Vh,
    const float* __restrict__ cw, u16* __restrict__ Xch)
{
  __shared__ __align__(16) u16 smem[19456];
  __shared__ float cws[33];

  const int ch = blockIdx.x;
  const int bh = blockIdx.y;
  const int tid = threadIdx.x;
  const int wave = tid >> 6, lane = tid & 63;
  const int lr = lane & 15, kg = lane >> 4;
  const int b = bh / H_, h = bh % H_;
  const int s0 = ch * 128;

  u16* Ph   = smem;
  u16* W2Th = smem + 9728;
  u16* W2Tl = smem + 14592;

  if (tid < 33) cws[tid] = cw[h * 33 + tid];
  for (int idx = tid; idx < 4096; idx += 256) {
    const int m = idx >> 6, d = idx & 63;
    const float w = W2[(size_t)bh * 4096 + idx];
    const _Float16 hh = (_Float16)w;
    W2Th[d * 76 + m] = f2h_bits(w);
    W2Tl[d * 76 + m] = f2h_bits(w - (float)hh);
  }

  const u16* Klb = Klh + (size_t)bh * 4096;
  const u16* Qb  = Qh + (size_t)bh * S_ * 64;
  f16x8 bf[4][2];
#pragma unroll
  for (int nt = 0; nt < 4; ++nt)
#pragma unroll
    for (int kk = 0; kk < 2; ++kk)
      bf[nt][kk] = *(const f16x8*)&Klb[(size_t)(nt * 16 + lr) * 64 + kk * 32 + kg * 8];

  f32x4 sacc[2][4];
#pragma unroll
  for (int t = 0; t < 2; ++t) {
#pragma unroll
    for (int nt = 0; nt < 4; ++nt) sacc[t][nt] = (f32x4){0.f, 0.f, 0.f, 0.f};
    const int rloc = wave * 32 + t * 16;
    f16x8 af[2];
#pragma unroll
    for (int kk = 0; kk < 2; ++kk)
      af[kk] = *(const f16x8*)&Qb[(size_t)(s0 + rloc + lr) * 64 + kk * 32 + kg * 8];
#pragma unroll
    for (int kk = 0; kk < 2; ++kk)
#pragma unroll
      for (int nt = 0; nt < 4; ++nt)
        sacc[t][nt] = __builtin_amdgcn_mfma_f32_16x16x32_f16(af[kk], bf[nt][kk], sacc[t][nt], 0, 0, 0);
  }

#pragma unroll
  for (int t = 0; t < 2; ++t)
#pragma unroll
    for (int nt = 0; nt < 4; ++nt)
      sacc[t][nt] *= 0.125f;

  float rinv[2][4];
#pragma unroll
  for (int t = 0; t < 2; ++t) {
#pragma unroll
    for (int r = 0; r < 4; ++r) {
      float mx = fmaxf(fmaxf(sacc[t][0][r], sacc[t][1][r]),
                       fmaxf(sacc[t][2][r], sacc[t][3][r]));
      mx = fmaxf(mx, __shfl_xor(mx, 1));
      mx = fmaxf(mx, __shfl_xor(mx, 2));
      mx = fmaxf(mx, __shfl_xor(mx, 4));
      mx = fmaxf(mx, __shfl_xor(mx, 8));
      float sum = 0.f;
#pragma unroll
      for (int nt = 0; nt < 4; ++nt) {
        const float e = expf(sacc[t][nt][r] - mx);
        sacc[t][nt][r] = e;
        sum += e;
      }
      sum += __shfl_xor(sum, 1);
      sum += __shfl_xor(sum, 2);
      sum += __shfl_xor(sum, 4);
      sum += __shfl_xor(sum, 8);
      rinv[t][r] = 1.f / sum;
    }
  }

#pragma unroll
  for (int t = 0; t < 2; ++t)
#pragma unroll
    for (int nt = 0; nt < 4; ++nt)
#pragma unroll
      for (int r = 0; r < 4; ++r) {
        const int row = wave * 32 + t * 16 + kg * 4 + r;
        Ph[row * 76 + nt * 16 + lr] = f2h_bits(sacc[t][nt][r] * rinv[t][r]);
      }
  __syncthreads();

  f32x4 oacc[2][4];
#pragma unroll
  for (int t = 0; t < 2; ++t)
#pragma unroll
    for (int dt = 0; dt < 4; ++dt) oacc[t][dt] = (f32x4){0.f, 0.f, 0.f, 0.f};
#pragma unroll
  for (int kk = 0; kk < 2; ++kk) {
    f16x8 pa[2];
#pragma unroll
    for (int t = 0; t < 2; ++t)
      pa[t] = *(const f16x8*)&Ph[(wave * 32 + t * 16 + lr) * 76 + kk * 32 + kg * 8];
#pragma unroll
    for (int dt = 0; dt < 4; ++dt) {
      const f16x8 wh = *(const f16x8*)&W2Th[(dt * 16 + lr) * 76 + kk * 32 + kg * 8];
      const f16x8 wl = *(const f16x8*)&W2Tl[(dt * 16 + lr) * 76 + kk * 32 + kg * 8];
#pragma unroll
      for (int t = 0; t < 2; ++t) {
        oacc[t][dt] = __builtin_amdgcn_mfma_f32_16x16x32_f16(pa[t], wh, oacc[t][dt], 0, 0, 0);
        oacc[t][dt] = __builtin_amdgcn_mfma_f32_16x16x32_f16(pa[t], wl, oacc[t][dt], 0, 0, 0);
      }
    }
  }
  __syncthreads();

  float* O = (float*)smem;
#pragma unroll
  for (int t = 0; t < 2; ++t)
#pragma unroll
    for (int dt = 0; dt < 4; ++dt)
#pragma unroll
      for (int r = 0; r < 4; ++r) {
        const int row = wave * 32 + t * 16 + kg * 4 + r;
        O[row * 68 + dt * 16 + lr] = oacc[t][dt][r];
      }
  __syncthreads();

  const int d = tid & 63, rg = tid >> 6;
  const int rbase = s0 + rg * 32;
  const u16* Vd = Vh + (size_t)bh * S_ * 64 + d;

  float v[40];
#pragma unroll
  for (int j = 0; j < 40; ++j) {
    const int sv = rbase - 16 + j;
    v[j] = (sv >= 0 && sv < S_) ? h2f(Vd[(size_t)sv * 64]) : 0.f;
  }

#pragma clang loop unroll(disable)
  for (int c = 0; c < 4; ++c) {
#pragma unroll
    for (int rr = 0; rr < 8; ++rr) {
      float acc = 0.f;
#pragma unroll
      for (int t = 0; t < 33; ++t) acc += v[rr + t] * cws[t];
      const int row = rg * 32 + c * 8 + rr;
      const float oo = O[row * 68 + d] + acc;
      const size_t idx = ((size_t)(b * S_ + s0 + row)) * HID_ + h * 64 + d;
      Xch[idx] = f2h_bits(oo);
    }
    if (c < 3) {
#pragma unroll
      for (int j = 0; j < 32; ++j) v[j] = v[j + 8];
#pragma unroll
      for (int j = 0; j < 8; ++j) {
        const int sv = rbase + 24 + c * 8 + j;
        v[32 + j] = (sv >= 0 && sv < S_) ? h2f(Vd[(size_t)sv * 64]) : 0.f;
      }
    }
  }
}

// =============================================================
extern "C" void kernel_launch(void* const* d_in, const int* in_sizes, int n_in,
                              void* d_out, int out_size, void* d_ws, size_t ws_size,
                              hipStream_t stream)
{
  (void)in_sizes; (void)n_in; (void)out_size; (void)ws_size;
  const float* x      = (const float*)d_in[0];
  const float* qkv_w  = (const float*)d_in[1];
  const float* qkv_b  = (const float*)d_in[2];
  const float* conv_w = (const float*)d_in[3];
  const float* out_w  = (const float*)d_in[4];
  const float* out_b  = (const float*)d_in[5];
  float* out = (float*)d_out;

  float* ws = (float*)d_ws;
  u16* Qh = (u16*)ws;
  u16* Kh = Qh + 6291456;
  u16* Vh = Kh + 6291456;
  float* Ql = ws + 9437184;
  float* Kl = Ql + 98304;
  float* K2 = Kl + 98304;
  float* W2 = K2 + 98304;
  float* colmax = W2 + 98304;
  float* rowmax = colmax + 32;
  u16* Klh = (u16*)(rowmax + 32);
  float* nxt = rowmax + 32 + 49152;
  u16* Xh  = (u16*)nxt;
  u16* Xl  = Xh + 6291456;
  u16* Wqh = Xl + 6291456;
  u16* Woh = Wqh + 1769472;
  u16* Xch = Xh;
  float* Opart = (float*)Xh;
  float* mpart = (float*)Xl;
  float* lpart = mpart + BH_ * NCH_ * 64;

  split3<<<(N8X + N8WQ + N8WO + 255) / 256, 256, 0, stream>>>(
      x, qkv_w, out_w, Xh, Wqh, Woh);

  gemm_bar<0><<<dim3(36, 64), 256, 0, stream>>>(
      Xh, Wqh, qkv_b, nullptr, Qh, Kh, Vh, Ql, Kl, Klh);

  kernel2_softmax<<<BH_, 256, 0, stream>>>(Ql, Kl, K2, colmax, rowmax);

  k3v_pass1<<<dim3(NCH_, BH_), 256, 0, stream>>>(Ql, Kh, Vh, Opart, mpart, lpart);

  newton_combine<<<BH_, 256, 0, stream>>>(K2, colmax, rowmax,
                                          Opart, mpart, lpart, W2);

  attn_conv_fused<<<dim3(NCH_, BH_), 256, 0, stream>>>(
      Qh, Klh, W2, Vh, conv_w, Xch);

  gemm_bar<1><<<dim3(6, 64), 256, 0, stream>>>(
      Xch, Woh, out_b, out, nullptr, nullptr, nullptr,
      nullptr, nullptr, nullptr);
}

// Round 19
// 193.039 us; speedup vs baseline: 1.4991x; 1.0473x over previous
//
#include <hip/hip_runtime.h>
#include <math.h>

#define B_   2
#define S_   4096
#define HID_ 768
#define H_   12
#define D_   64
#define M_   64
#define CK_  33
#define BH_  (B_*H_)   // 24
#define KD_  768
#define NCH_ 32        // S-chunks (128 rows each)
#define SC_  128       // keys per chunk

typedef float  f32x4  __attribute__((ext_vector_type(4)));
typedef _Float16 f16x8 __attribute__((ext_vector_type(8)));
typedef unsigned short u16;

__device__ __forceinline__ u16 f2h_bits(float f) {
  union { _Float16 h; u16 u; } c; c.h = (_Float16)f; return c.u;
}
__device__ __forceinline__ float h2f(u16 b) {
  union { _Float16 h; u16 u; } c; c.u = b; return (float)c.h;
}
__device__ __forceinline__ void cvt8_hl(const float4 a, const float4 b,
                                        f16x8* hi, f16x8* lo) {
  const float v[8] = {a.x, a.y, a.z, a.w, b.x, b.y, b.z, b.w};
  f16x8 H, L;
#pragma unroll
  for (int e = 0; e < 8; ++e) {
    const _Float16 hh = (_Float16)v[e];
    H[e] = hh;
    L[e] = (_Float16)(v[e] - (float)hh);
  }
  *hi = H; *lo = L;
}
__device__ __forceinline__ void wsplit(u16* Hh, u16* Hl, int idx, float v) {
  const _Float16 hh = (_Float16)v;
  Hh[idx] = f2h_bits(v);
  Hl[idx] = f2h_bits(v - (float)hh);
}

__device__ __forceinline__ void gld16(const void* g, void* l) {
  __builtin_amdgcn_global_load_lds(
      (const __attribute__((address_space(1))) void*)g,
      (__attribute__((address_space(3))) void*)l, 16, 0, 0);
}

// =============================================================
// Downcast: x -> Xh, qkv_w -> Wqh, out_w -> Woh (fp16 hi only)
// =============================================================
#define N8X  786432
#define N8WQ 221184
#define N8WO 73728
__global__ __launch_bounds__(256) void split3(
    const float* __restrict__ x, const float* __restrict__ qkv_w,
    const float* __restrict__ out_w,
    u16* __restrict__ Xh, u16* __restrict__ Wqh, u16* __restrict__ Woh)
{
  const int i = blockIdx.x * 256 + threadIdx.x;
  const float* src; u16* dst; int j;
  if (i < N8X)                 { src = x;     dst = Xh;  j = i; }
  else if (i < N8X + N8WQ)     { src = qkv_w; dst = Wqh; j = i - N8X; }
  else if (i < N8X + N8WQ + N8WO) { src = out_w; dst = Woh; j = i - N8X - N8WQ; }
  else return;
  const float4 a = ((const float4*)src)[2 * j], b = ((const float4*)src)[2 * j + 1];
  const float v[8] = {a.x, a.y, a.z, a.w, b.x, b.y, b.z, b.w};
  union { u16 u[8]; uint4 q; } hv;
#pragma unroll
  for (int e = 0; e < 8; ++e) hv.u[e] = f2h_bits(v[e]);
  ((uint4*)dst)[j] = hv.q;
}

// =============================================================
// fp16 MFMA GEMM, 128x128 tile both modes, single product.
// 4 waves, global_load_lds dbuf staging, counted vmcnt + raw barriers.
// MODE 0: scatter Q/K/V fp16 + fused landmarks (wave = 1 seg x 1 head).
// MODE 1: row-major f32 out.
// =============================================================
template<int MODE>
__global__ __launch_bounds__(256) void gemm_bar(
    const u16* __restrict__ Ahg, const u16* __restrict__ Bhg,
    const float* __restrict__ bias,
    float* __restrict__ oF, u16* __restrict__ oQ, u16* __restrict__ oK,
    u16* __restrict__ oV,
    float* __restrict__ Ql, float* __restrict__ Kl, u16* __restrict__ Klh)
{
  constexpr int NBX = (MODE == 0) ? 18 : 6;
  constexpr int ABUF = 128 * 32;           // u16 per A buf
  constexpr int BUFSZ = 2 * ABUF;          // A + B
  constexpr int NT = KD_ / 32;
  constexpr int NWG = NBX * 64;
  constexpr int CPX = NWG / 8;

  __shared__ __align__(16) u16 lds[2][BUFSZ];

  const int tid = threadIdx.x;
  const int lin = blockIdx.y * NBX + blockIdx.x;
  const int swb = (lin & 7) * CPX + (lin >> 3);   // XCD-contiguous chunks
  const int m0 = (swb / NBX) * 128;
  const int n0 = (swb % NBX) * 128;

  const int wave = tid >> 6, lane = tid & 63;
  const int wm = wave >> 1, wn = wave & 1;
  const int lr = lane & 15, kg = lane >> 4;

  const int srow = tid >> 2;
  const int swz_s = (tid >> 3) & 3;
  const int sk = ((tid & 3) ^ swz_s) * 8;

  const u16* pA = Ahg + (size_t)(m0 + srow) * KD_ + sk;
  const u16* pB = Bhg + (size_t)(n0 + srow) * KD_ + sk;

  f32x4 acc[4][4];
#pragma unroll
  for (int i = 0; i < 4; ++i)
#pragma unroll
    for (int j = 0; j < 4; ++j) acc[i][j] = (f32x4){0.f, 0.f, 0.f, 0.f};

  const int rsw = (lr >> 1) & 3;
  const int kq = (kg ^ rsw) * 8;
  const int abase = (wm * 64 + lr) * 32 + kq;
  const int bbase = (wn * 64 + lr) * 32 + kq;

#define STAGE_(buf, kt) do {                                              \
    const size_t go_ = (size_t)(kt) * 32;                                 \
    u16* L_ = &lds[buf][0];                                               \
    gld16(pA + go_,            L_ + tid * 8);                             \
    gld16(pA + go_ + 64 * KD_, L_ + 2048 + tid * 8);                      \
    gld16(pB + go_,            L_ + ABUF + tid * 8);                      \
    gld16(pB + go_ + 64 * KD_, L_ + ABUF + 2048 + tid * 8);               \
  } while (0)

  STAGE_(0, 0);

  int cur = 0;
  for (int kt = 0; kt < NT; ++kt) {
    if (kt + 1 < NT) {
      STAGE_(cur ^ 1, kt + 1);
      asm volatile("s_waitcnt vmcnt(4)" ::: "memory");   // prev stage only
    } else {
      asm volatile("s_waitcnt vmcnt(0)" ::: "memory");
    }
    __builtin_amdgcn_s_barrier();
    __builtin_amdgcn_sched_barrier(0);

    const u16* L_ = &lds[cur][0];
    f16x8 af[4], bf[4];
#pragma unroll
    for (int i = 0; i < 4; ++i) af[i] = *(const f16x8*)&L_[abase + i * 512];
#pragma unroll
    for (int j = 0; j < 4; ++j) bf[j] = *(const f16x8*)&L_[ABUF + bbase + j * 512];
#pragma unroll
    for (int i = 0; i < 4; ++i)
#pragma unroll
      for (int j = 0; j < 4; ++j)
        acc[i][j] = __builtin_amdgcn_mfma_f32_16x16x32_f16(af[i], bf[j], acc[i][j], 0, 0, 0);

    __builtin_amdgcn_sched_barrier(0);
    __builtin_amdgcn_s_barrier();
    cur ^= 1;
  }
#undef STAGE_

  if (MODE == 0) {
    const int ncol0 = n0 + wn * 64;                  // wave's head start
    const int part = ncol0 / 768;
    const int h0 = (ncol0 - part * 768) >> 6;
    u16* base = (part == 0) ? oQ : ((part == 1) ? oK : oV);
#pragma unroll
    for (int i = 0; i < 4; ++i) {
      const int mbase = m0 + wm * 64 + i * 16 + kg * 4;
#pragma unroll
      for (int j = 0; j < 4; ++j) {
        const int d = j * 16 + lr;
        const float bv = bias[ncol0 + d];
#pragma unroll
        for (int r = 0; r < 4; ++r) {
          const int row = mbase + r;
          const int b = row >> 12, s = row & (S_ - 1);
          base[(((size_t)(b * H_ + h0) * S_ + s) << 6) + d] = f2h_bits(acc[i][j][r] + bv);
        }
      }
    }
    // landmarks: wave's 64 rows = one full segment of one (b, h0)
    if (part < 2) {
      const int rowseg = m0 + wm * 64;
      const int b = rowseg >> 12;
      const int seg = (rowseg & (S_ - 1)) >> 6;
      const int bhh = b * H_ + h0;
      float* dst = (part == 0) ? Ql : Kl;
#pragma unroll
      for (int j = 0; j < 4; ++j) {
        float sj = 0.f;
#pragma unroll
        for (int i = 0; i < 4; ++i)
#pragma unroll
          for (int r = 0; r < 4; ++r) sj += acc[i][j][r];
        sj += __shfl_xor(sj, 16);
        sj += __shfl_xor(sj, 32);
        if (kg == 0) {
          const int d = j * 16 + lr;
          const float lm = sj * (1.f / 64.f) + bias[ncol0 + d];
          dst[((size_t)bhh * M_ + seg) * 64 + d] = lm;
          if (part == 1) Klh[((size_t)bhh * M_ + seg) * 64 + d] = f2h_bits(lm);
        }
      }
    }
  } else {
#pragma unroll
    for (int i = 0; i < 4; ++i) {
      const int mbase = m0 + wm * 64 + i * 16 + kg * 4;
#pragma unroll
      for (int j = 0; j < 4; ++j) {
        const int ncol = n0 + wn * 64 + j * 16 + lr;
        const float bv = bias[ncol];
#pragma unroll
        for (int r = 0; r < 4; ++r) {
          const int row = mbase + r;
          oF[(size_t)row * HID_ + ncol] = acc[i][j][r] + bv;
        }
      }
    }
  }
}

// =============================================================
// kernel_2 softmax + per-(b,h) max col/row sums (unchanged)
// =============================================================
__global__ __launch_bounds__(256) void kernel2_softmax(
    const float* __restrict__ Ql, const float* __restrict__ Kl,
    float* __restrict__ K2, float* __restrict__ colmax, float* __restrict__ rowmax)
{
  __shared__ float Qs[64][68], Ks[64][68], S2[64][68];
  __shared__ float red1[64], red2[64];
  const int bh = blockIdx.x, tid = threadIdx.x;
  for (int idx = tid; idx < 4096; idx += 256) {
    const int r = idx >> 6, c = idx & 63;
    Qs[r][c] = Ql[(size_t)bh * 4096 + idx];
    Ks[r][c] = Kl[(size_t)bh * 4096 + idx];
  }
  __syncthreads();
  for (int idx = tid; idx < 4096; idx += 256) {
    const int r = idx >> 6, c = idx & 63;
    float dot = 0.f;
#pragma unroll
    for (int k = 0; k < 64; k += 4) {
      const float4 a = *(const float4*)&Qs[r][k];
      const float4 b = *(const float4*)&Ks[c][k];
      dot += a.x * b.x + a.y * b.y + a.z * b.z + a.w * b.w;
    }
    S2[r][c] = dot * 0.125f;
  }
  __syncthreads();
  if (tid < 64) {
    const int r = tid;
    float mx = -1e30f;
    for (int c = 0; c < 64; ++c) mx = fmaxf(mx, S2[r][c]);
    float sum = 0.f;
    for (int c = 0; c < 64; ++c) { const float e = expf(S2[r][c] - mx); S2[r][c] = e; sum += e; }
    const float inv = 1.f / sum;
    for (int c = 0; c < 64; ++c) S2[r][c] *= inv;
  }
  __syncthreads();
  for (int idx = tid; idx < 4096; idx += 256)
    K2[(size_t)bh * 4096 + idx] = S2[idx >> 6][idx & 63];
  if (tid < 64) {
    float cs = 0.f, rs = 0.f;
    for (int m = 0; m < 64; ++m) { cs += S2[m][tid]; rs += S2[tid][m]; }
    red1[tid] = cs; red2[tid] = rs;
  }
  __syncthreads();
  if (tid == 0) {
    float mc = 0.f, mr = 0.f;
    for (int i = 0; i < 64; ++i) { mc = fmaxf(mc, red1[i]); mr = fmaxf(mr, red2[i]); }
    colmax[bh] = mc; rowmax[bh] = mr;
  }
}

// =============================================================
// MFMA Newton-Schulz + combine + W2 (unchanged)
// =============================================================
#define NST 88
__device__ __forceinline__ void mfma64x64(
    const u16* Ah, const u16* Al, const u16* Bh, const u16* Bl,
    int wave, int lr, int kg, f32x4 C[4])
{
#pragma unroll
  for (int j = 0; j < 4; ++j) C[j] = (f32x4){0.f, 0.f, 0.f, 0.f};
#pragma unroll
  for (int kk = 0; kk < 2; ++kk) {
    const int ao = (wave * 16 + lr) * NST + kk * 32 + kg * 8;
    const f16x8 ah = *(const f16x8*)&Ah[ao];
    const f16x8 al = *(const f16x8*)&Al[ao];
#pragma unroll
    for (int j = 0; j < 4; ++j) {
      const int bo = (j * 16 + lr) * NST + kk * 32 + kg * 8;
      const f16x8 bh = *(const f16x8*)&Bh[bo];
      const f16x8 bl = *(const f16x8*)&Bl[bo];
      C[j] = __builtin_amdgcn_mfma_f32_16x16x32_f16(ah, bh, C[j], 0, 0, 0);
      C[j] = __builtin_amdgcn_mfma_f32_16x16x32_f16(ah, bl, C[j], 0, 0, 0);
      C[j] = __builtin_amdgcn_mfma_f32_16x16x32_f16(al, bh, C[j], 0, 0, 0);
    }
  }
}

__global__ __launch_bounds__(256) void newton_combine(
    const float* __restrict__ K2, const float* __restrict__ colmax,
    const float* __restrict__ rowmax,
    const float* __restrict__ Opart, const float* __restrict__ mpart,
    const float* __restrict__ lpart, float* __restrict__ W2)
{
  __shared__ __align__(16) u16 K2h[64*NST], K2l[64*NST];
  __shared__ __align__(16) u16 Vh_[64*NST], Vl_[64*NST];
  __shared__ __align__(16) u16 VTh[64*NST], VTl[64*NST];
  __shared__ __align__(16) u16 KVh[64*NST], KVl[64*NST];
  __shared__ __align__(16) u16 TTh[64*NST], TTl[64*NST];
  __shared__ float w_[64][33];
  __shared__ float scale_s;

  const int bh = blockIdx.x, tid = threadIdx.x;
  const int wave = tid >> 6, lane = tid & 63;
  const int lr = lane & 15, kg = lane >> 4;

  if (tid == 0) {
    float mc = 0.f, mr = 0.f;
    for (int i = 0; i < BH_; ++i) { mc = fmaxf(mc, colmax[i]); mr = fmaxf(mr, rowmax[i]); }
    scale_s = 1.f / (mc * mr);
  }
  __syncthreads();
  const float scale = scale_s;

  for (int idx = tid; idx < 4096; idx += 256) {
    const int r = idx >> 6, c = idx & 63;
    const float v = K2[(size_t)bh * 4096 + idx];
    wsplit(K2h, K2l, r * NST + c, v);
    const float sv = scale * v;
    wsplit(VTh, VTl, r * NST + c, sv);
    wsplit(Vh_, Vl_, c * NST + r, sv);
  }
  __syncthreads();

  f32x4 C[4];
  for (int it = 0; it < 6; ++it) {
    mfma64x64(K2h, K2l, VTh, VTl, wave, lr, kg, C);
#pragma unroll
    for (int j = 0; j < 4; ++j)
#pragma unroll
      for (int r = 0; r < 4; ++r) {
        const int row = wave * 16 + kg * 4 + r, col = j * 16 + lr;
        const float kv = C[j][r];
        wsplit(KVh, KVl, row * NST + col, kv);
        wsplit(TTh, TTl, col * NST + row, (row == col ? 7.f : 0.f) - kv);
      }
    __syncthreads();
    mfma64x64(KVh, KVl, TTh, TTl, wave, lr, kg, C);
    __syncthreads();
#pragma unroll
    for (int j = 0; j < 4; ++j)
#pragma unroll
      for (int r = 0; r < 4; ++r) {
        const int row = wave * 16 + kg * 4 + r, col = j * 16 + lr;
        wsplit(TTh, TTl, col * NST + row, (row == col ? 15.f : 0.f) - C[j][r]);
      }
    __syncthreads();
    mfma64x64(KVh, KVl, TTh, TTl, wave, lr, kg, C);
    __syncthreads();
#pragma unroll
    for (int j = 0; j < 4; ++j)
#pragma unroll
      for (int r = 0; r < 4; ++r) {
        const int row = wave * 16 + kg * 4 + r, col = j * 16 + lr;
        wsplit(TTh, TTl, col * NST + row, (row == col ? 13.f : 0.f) - C[j][r]);
      }
    __syncthreads();
    mfma64x64(Vh_, Vl_, TTh, TTl, wave, lr, kg, C);
#pragma unroll
    for (int j = 0; j < 4; ++j)
#pragma unroll
      for (int r = 0; r < 4; ++r) {
        const int row = wave * 16 + kg * 4 + r, col = j * 16 + lr;
        const float v = 0.25f * C[j][r];
        wsplit(Vh_, Vl_, row * NST + col, v);
        wsplit(VTh, VTl, col * NST + row, v);
      }
    __syncthreads();
  }

  if (tid < 64) {
    const int m = tid;
    float Mx = -1e30f;
    for (int j = 0; j < NCH_; ++j)
      Mx = fmaxf(Mx, mpart[((size_t)bh * NCH_ + j) * 64 + m]);
    float denom = 0.f;
    for (int j = 0; j < NCH_; ++j)
      denom += expf(mpart[((size_t)bh * NCH_ + j) * 64 + m] - Mx) *
               lpart[((size_t)bh * NCH_ + j) * 64 + m];
    const float inv = 1.f / denom;
    for (int j = 0; j < NCH_; ++j)
      w_[m][j] = expf(mpart[((size_t)bh * NCH_ + j) * 64 + m] - Mx) * inv;
  }
  __syncthreads();
  u16* W1Th = K2h;
  u16* W1Tl = K2l;
  {
    const int mg = tid >> 4, dq = (tid & 15) * 4;
#pragma unroll
    for (int i = 0; i < 4; ++i) {
      const int m = mg * 4 + i;
      float4 acc = make_float4(0.f, 0.f, 0.f, 0.f);
      for (int j = 0; j < NCH_; ++j) {
        const float ww = w_[m][j];
        const float4 o = *(const float4*)&Opart[(((size_t)bh * NCH_ + j) * 64 + m) * 64 + dq];
        acc.x += ww * o.x; acc.y += ww * o.y; acc.z += ww * o.z; acc.w += ww * o.w;
      }
      wsplit(W1Th, W1Tl, (dq + 0) * NST + m, acc.x);
      wsplit(W1Th, W1Tl, (dq + 1) * NST + m, acc.y);
      wsplit(W1Th, W1Tl, (dq + 2) * NST + m, acc.z);
      wsplit(W1Th, W1Tl, (dq + 3) * NST + m, acc.w);
    }
  }
  __syncthreads();
  mfma64x64(Vh_, Vl_, W1Th, W1Tl, wave, lr, kg, C);
#pragma unroll
  for (int j = 0; j < 4; ++j)
#pragma unroll
    for (int r = 0; r < 4; ++r) {
      const int row = wave * 16 + kg * 4 + r, col = j * 16 + lr;
      W2[(size_t)bh * 4096 + row * 64 + col] = C[j][r];
    }
}

// =============================================================
// k3v pass 1 (unchanged)
// =============================================================
__global__ __launch_bounds__(256) void k3v_pass1(
    const float* __restrict__ Ql, const u16* __restrict__ Kh,
    const u16* __restrict__ Vh, float* __restrict__ Opart,
    float* __restrict__ mpart, float* __restrict__ lpart)
{
  __shared__ float P[64][129];
  __shared__ float red1[64][4], red2[64][4];

  const int ch = blockIdx.x;
  const int bh = blockIdx.y;
  const int tid = threadIdx.x;
  const int wave = tid >> 6, lane = tid & 63;
  const int lr = lane & 15, kg = lane >> 4;

  const float* Qlb = Ql + (size_t)bh * 4096;
  const u16*   Kb  = Kh + (size_t)bh * S_ * 64;
  const u16*   Vb  = Vh + (size_t)bh * S_ * 64;

  f16x8 ah[4][2], al[4][2];
#pragma unroll
  for (int mt = 0; mt < 4; ++mt)
#pragma unroll
    for (int kk = 0; kk < 2; ++kk) {
      const float* qr = Qlb + (size_t)(mt * 16 + lr) * 64 + kk * 32 + kg * 8;
      cvt8_hl(*(const float4*)qr, *(const float4*)(qr + 4), &ah[mt][kk], &al[mt][kk]);
    }

#pragma unroll
  for (int t = 0; t < 2; ++t) {
    const int s0 = (wave * 2 + t) * 16;
    const int srow = ch * SC_ + s0 + lr;
    f32x4 acc[4];
#pragma unroll
    for (int mt = 0; mt < 4; ++mt) acc[mt] = (f32x4){0.f, 0.f, 0.f, 0.f};
#pragma unroll
    for (int kk = 0; kk < 2; ++kk) {
      const f16x8 bhf = *(const f16x8*)&Kb[(size_t)srow * 64 + kk * 32 + kg * 8];
#pragma unroll
      for (int mt = 0; mt < 4; ++mt) {
        acc[mt] = __builtin_amdgcn_mfma_f32_16x16x32_f16(ah[mt][kk], bhf, acc[mt], 0, 0, 0);
        acc[mt] = __builtin_amdgcn_mfma_f32_16x16x32_f16(al[mt][kk], bhf, acc[mt], 0, 0, 0);
      }
    }
#pragma unroll
    for (int mt = 0; mt < 4; ++mt)
#pragma unroll
      for (int r = 0; r < 4; ++r)
        P[mt * 16 + kg * 4 + r][s0 + lr] = acc[mt][r] * 0.125f;
  }
  __syncthreads();

  const int r = tid >> 2, q = tid & 3;
  {
    float mx = -1e30f;
#pragma unroll
    for (int s = 0; s < 32; ++s) mx = fmaxf(mx, P[r][q * 32 + s]);
    red1[r][q] = mx;
  }
  __syncthreads();
  const float rowmax = fmaxf(fmaxf(red1[r][0], red1[r][1]),
                             fmaxf(red1[r][2], red1[r][3]));
  {
    float sum = 0.f;
#pragma unroll
    for (int s = 0; s < 32; ++s) {
      const float e = expf(P[r][q * 32 + s] - rowmax);
      P[r][q * 32 + s] = e;
      sum += e;
    }
    red2[r][q] = sum;
  }
  __syncthreads();
  if (q == 0) {
    const float rowsum = red2[r][0] + red2[r][1] + red2[r][2] + red2[r][3];
    mpart[((size_t)bh * NCH_ + ch) * 64 + r] = rowmax;
    lpart[((size_t)bh * NCH_ + ch) * 64 + r] = rowsum;
  }

  const int mg = tid >> 4, dq = (tid & 15) * 4;
  float4 oacc[4];
#pragma unroll
  for (int i = 0; i < 4; ++i) oacc[i] = make_float4(0.f, 0.f, 0.f, 0.f);
  for (int s = 0; s < SC_; ++s) {
    const ushort4 vv = *(const ushort4*)&Vb[(size_t)(ch * SC_ + s) * 64 + dq];
    const float4 v = make_float4(h2f(vv.x), h2f(vv.y), h2f(vv.z), h2f(vv.w));
#pragma unroll
    for (int i = 0; i < 4; ++i) {
      const float p = P[mg * 4 + i][s];
      oacc[i].x += p * v.x; oacc[i].y += p * v.y;
      oacc[i].z += p * v.z; oacc[i].w += p * v.w;
    }
  }
#pragma unroll
  for (int i = 0; i < 4; ++i) {
    const size_t o = (((size_t)bh * NCH_ + ch) * 64 + mg * 4 + i) * 64 + dq;
    *(float4*)&Opart[o] = oacc[i];
  }
}

// =============================================================
// FUSED attention + conv v4 (Xch hi-only out, unchanged)
// =============================================================
__global__ __launch_bounds__(256) void attn_conv_fused(
    const u16* __restrict__ Qh, const u16* __restrict__ Klh,
    const float* __restrict__ W2, const u16* __restrict__ Vh,
    const float* __restrict__ cw, u16* __restrict__ Xch)
{
  __shared__ __align__(16) u16 smem[19456];
  __shared__ float cws[33];

  const int ch = blockIdx.x;
  const int bh = blockIdx.y;
  const int tid = threadIdx.x;
  const int wave = tid >> 6, lane = tid & 63;
  const int lr = lane & 15, kg = lane >> 4;
  const int b = bh / H_, h = bh % H_;
  const int s0 = ch * 128;

  u16* Ph   = smem;
  u16* W2Th = smem + 9728;
  u16* W2Tl = smem + 14592;

  if (tid < 33) cws[tid] = cw[h * 33 + tid];
  for (int idx = tid; idx < 4096; idx += 256) {
    const int m = idx >> 6, d = idx & 63;
    const float w = W2[(size_t)bh * 4096 + idx];
    const _Float16 hh = (_Float16)w;
    W2Th[d * 76 + m] = f2h_bits(w);
    W2Tl[d * 76 + m] = f2h_bits(w - (float)hh);
  }

  const u16* Klb = Klh + (size_t)bh * 4096;
  const u16* Qb  = Qh + (size_t)bh * S_ * 64;
  f16x8 bf[4][2];
#pragma unroll
  for (int nt = 0; nt < 4; ++nt)
#pragma unroll
    for (int kk = 0; kk < 2; ++kk)
      bf[nt][kk] = *(const f16x8*)&Klb[(size_t)(nt * 16 + lr) * 64 + kk * 32 + kg * 8];

  f32x4 sacc[2][4];
#pragma unroll
  for (int t = 0; t < 2; ++t) {
#pragma unroll
    for (int nt = 0; nt < 4; ++nt) sacc[t][nt] = (f32x4){0.f, 0.f, 0.f, 0.f};
    const int rloc = wave * 32 + t * 16;
    f16x8 af[2];
#pragma unroll
    for (int kk = 0; kk < 2; ++kk)
      af[kk] = *(const f16x8*)&Qb[(size_t)(s0 + rloc + lr) * 64 + kk * 32 + kg * 8];
#pragma unroll
    for (int kk = 0; kk < 2; ++kk)
#pragma unroll
      for (int nt = 0; nt < 4; ++nt)
        sacc[t][nt] = __builtin_amdgcn_mfma_f32_16x16x32_f16(af[kk], bf[nt][kk], sacc[t][nt], 0, 0, 0);
  }

#pragma unroll
  for (int t = 0; t < 2; ++t)
#pragma unroll
    for (int nt = 0; nt < 4; ++nt)
      sacc[t][nt] *= 0.125f;

  float rinv[2][4];
#pragma unroll
  for (int t = 0; t < 2; ++t) {
#pragma unroll
    for (int r = 0; r < 4; ++r) {
      float mx = fmaxf(fmaxf(sacc[t][0][r], sacc[t][1][r]),
                       fmaxf(sacc[t][2][r], sacc[t][3][r]));
      mx = fmaxf(mx, __shfl_xor(mx, 1));
      mx = fmaxf(mx, __shfl_xor(mx, 2));
      mx = fmaxf(mx, __shfl_xor(mx, 4));
      mx = fmaxf(mx, __shfl_xor(mx, 8));
      float sum = 0.f;
#pragma unroll
      for (int nt = 0; nt < 4; ++nt) {
        const float e = expf(sacc[t][nt][r] - mx);
        sacc[t][nt][r] = e;
        sum += e;
      }
      sum += __shfl_xor(sum, 1);
      sum += __shfl_xor(sum, 2);
      sum += __shfl_xor(sum, 4);
      sum += __shfl_xor(sum, 8);
      rinv[t][r] = 1.f / sum;
    }
  }

#pragma unroll
  for (int t = 0; t < 2; ++t)
#pragma unroll
    for (int nt = 0; nt < 4; ++nt)
#pragma unroll
      for (int r = 0; r < 4; ++r) {
        const int row = wave * 32 + t * 16 + kg * 4 + r;
        Ph[row * 76 + nt * 16 + lr] = f2h_bits(sacc[t][nt][r] * rinv[t][r]);
      }
  __syncthreads();

  f32x4 oacc[2][4];
#pragma unroll
  for (int t = 0; t < 2; ++t)
#pragma unroll
    for (int dt = 0; dt < 4; ++dt) oacc[t][dt] = (f32x4){0.f, 0.f, 0.f, 0.f};
#pragma unroll
  for (int kk = 0; kk < 2; ++kk) {
    f16x8 pa[2];
#pragma unroll
    for (int t = 0; t < 2; ++t)
      pa[t] = *(const f16x8*)&Ph[(wave * 32 + t * 16 + lr) * 76 + kk * 32 + kg * 8];
#pragma unroll
    for (int dt = 0; dt < 4; ++dt) {
      const f16x8 wh = *(const f16x8*)&W2Th[(dt * 16 + lr) * 76 + kk * 32 + kg * 8];
      const f16x8 wl = *(const f16x8*)&W2Tl[(dt * 16 + lr) * 76 + kk * 32 + kg * 8];
#pragma unroll
      for (int t = 0; t < 2; ++t) {
        oacc[t][dt] = __builtin_amdgcn_mfma_f32_16x16x32_f16(pa[t], wh, oacc[t][dt], 0, 0, 0);
        oacc[t][dt] = __builtin_amdgcn_mfma_f32_16x16x32_f16(pa[t], wl, oacc[t][dt], 0, 0, 0);
      }
    }
  }
  __syncthreads();

  float* O = (float*)smem;
#pragma unroll
  for (int t = 0; t < 2; ++t)
#pragma unroll
    for (int dt = 0; dt < 4; ++dt)
#pragma unroll
      for (int r = 0; r < 4; ++r) {
        const int row = wave * 32 + t * 16 + kg * 4 + r;
        O[row * 68 + dt * 16 + lr] = oacc[t][dt][r];
      }
  __syncthreads();

  const int d = tid & 63, rg = tid >> 6;
  const int rbase = s0 + rg * 32;
  const u16* Vd = Vh + (size_t)bh * S_ * 64 + d;

  float v[40];
#pragma unroll
  for (int j = 0; j < 40; ++j) {
    const int sv = rbase - 16 + j;
    v[j] = (sv >= 0 && sv < S_) ? h2f(Vd[(size_t)sv * 64]) : 0.f;
  }

#pragma clang loop unroll(disable)
  for (int c = 0; c < 4; ++c) {
#pragma unroll
    for (int rr = 0; rr < 8; ++rr) {
      float acc = 0.f;
#pragma unroll
      for (int t = 0; t < 33; ++t) acc += v[rr + t] * cws[t];
      const int row = rg * 32 + c * 8 + rr;
      const float oo = O[row * 68 + d] + acc;
      const size_t idx = ((size_t)(b * S_ + s0 + row)) * HID_ + h * 64 + d;
      Xch[idx] = f2h_bits(oo);
    }
    if (c < 3) {
#pragma unroll
      for (int j = 0; j < 32; ++j) v[j] = v[j + 8];
#pragma unroll
      for (int j = 0; j < 8; ++j) {
        const int sv = rbase + 24 + c * 8 + j;
        v[32 + j] = (sv >= 0 && sv < S_) ? h2f(Vd[(size_t)sv * 64]) : 0.f;
      }
    }
  }
}

// =============================================================
extern "C" void kernel_launch(void* const* d_in, const int* in_sizes, int n_in,
                              void* d_out, int out_size, void* d_ws, size_t ws_size,
                              hipStream_t stream)
{
  (void)in_sizes; (void)n_in; (void)out_size; (void)ws_size;
  const float* x      = (const float*)d_in[0];
  const float* qkv_w  = (const float*)d_in[1];
  const float* qkv_b  = (const float*)d_in[2];
  const float* conv_w = (const float*)d_in[3];
  const float* out_w  = (const float*)d_in[4];
  const float* out_b  = (const float*)d_in[5];
  float* out = (float*)d_out;

  float* ws = (float*)d_ws;
  u16* Qh = (u16*)ws;
  u16* Kh = Qh + 6291456;
  u16* Vh = Kh + 6291456;
  float* Ql = ws + 9437184;
  float* Kl = Ql + 98304;
  float* K2 = Kl + 98304;
  float* W2 = K2 + 98304;
  float* colmax = W2 + 98304;
  float* rowmax = colmax + 32;
  u16* Klh = (u16*)(rowmax + 32);
  float* nxt = rowmax + 32 + 49152;
  u16* Xh  = (u16*)nxt;
  u16* Xl  = Xh + 6291456;
  u16* Wqh = Xl + 6291456;
  u16* Woh = Wqh + 1769472;
  u16* Xch = Xh;
  float* Opart = (float*)Xh;
  float* mpart = (float*)Xl;
  float* lpart = mpart + BH_ * NCH_ * 64;

  split3<<<(N8X + N8WQ + N8WO + 255) / 256, 256, 0, stream>>>(
      x, qkv_w, out_w, Xh, Wqh, Woh);

  gemm_bar<0><<<dim3(18, 64), 256, 0, stream>>>(
      Xh, Wqh, qkv_b, nullptr, Qh, Kh, Vh, Ql, Kl, Klh);

  kernel2_softmax<<<BH_, 256, 0, stream>>>(Ql, Kl, K2, colmax, rowmax);

  k3v_pass1<<<dim3(NCH_, BH_), 256, 0, stream>>>(Ql, Kh, Vh, Opart, mpart, lpart);

  newton_combine<<<BH_, 256, 0, stream>>>(K2, colmax, rowmax,
                                          Opart, mpart, lpart, W2);

  attn_conv_fused<<<dim3(NCH_, BH_), 256, 0, stream>>>(
      Qh, Klh, W2, Vh, conv_w, Xch);

  gemm_bar<1><<<dim3(6, 64), 256, 0, stream>>>(
      Xch, Woh, out_b, out, nullptr, nullptr, nullptr,
      nullptr, nullptr, nullptr);
}